// Round 1
// baseline (708.801 us; speedup 1.0000x reference)
//
#include <hip/hip_runtime.h>
#include <hip/hip_bf16.h>
#include <math.h>

// Problem constants (fixed by reference)
#define BB 4
#define SS 2048
#define DD 512
#define HH 8
#define DHH 64
#define DFF 2048
#define MM (BB*SS)          // 8192 rows
#define QKV_N (3*DD)        // 1536

// ---------------------------------------------------------------- LayerNorm
__global__ __launch_bounds__(128)
void ln_kernel(const float* __restrict__ x, const float* __restrict__ g,
               const float* __restrict__ beta, float* __restrict__ out)
{
    const int row = blockIdx.x;
    const int t = threadIdx.x;               // 128 threads, 4 floats each
    const float4 v = reinterpret_cast<const float4*>(x + (size_t)row * DD)[t];

    float s  = v.x + v.y + v.z + v.w;
    float s2 = v.x*v.x + v.y*v.y + v.z*v.z + v.w*v.w;
    #pragma unroll
    for (int off = 32; off >= 1; off >>= 1) {
        s  += __shfl_xor(s,  off);
        s2 += __shfl_xor(s2, off);
    }
    __shared__ float red[2][2];
    const int lane = t & 63, wid = t >> 6;
    if (lane == 0) { red[wid][0] = s; red[wid][1] = s2; }
    __syncthreads();
    const float ts  = red[0][0] + red[1][0];
    const float ts2 = red[0][1] + red[1][1];
    const float mu  = ts * (1.0f / DD);
    const float var = ts2 * (1.0f / DD) - mu * mu;
    const float rs  = rsqrtf(var + 1e-5f);

    const float4 gv = reinterpret_cast<const float4*>(g)[t];
    const float4 bv = reinterpret_cast<const float4*>(beta)[t];
    float4 o;
    o.x = (v.x - mu) * rs * gv.x + bv.x;
    o.y = (v.y - mu) * rs * gv.y + bv.y;
    o.z = (v.z - mu) * rs * gv.z + bv.z;
    o.w = (v.w - mu) * rs * gv.w + bv.w;
    reinterpret_cast<float4*>(out + (size_t)row * DD)[t] = o;
}

// ---------------------------------------------------------------- SGEMM
// C[m,n] = sum_k A[m,k] * W[n,k] + bias[n]   (+ residual / gelu epilogues)
// A: [M,K] row-major, W: [N,K] row-major (both K-contiguous -> coalesced).
// EPI: 0 = bias, 1 = bias + residual add, 2 = bias + exact GELU
template<int BM, int BN, int TM, int TN, int EPI>
__global__ __launch_bounds__(256)
void sgemm_kernel(const float* __restrict__ A, const float* __restrict__ W,
                  const float* __restrict__ bias, const float* __restrict__ Res,
                  float* __restrict__ C, int M, int N, int K)
{
    constexpr int BK  = 16;
    constexpr int PAD = 4;
    constexpr int LDA = BM + PAD;
    constexpr int LDB = BN + PAD;
    __shared__ float As[BK][LDA];   // k-major (transposed) tiles
    __shared__ float Ws[BK][LDB];

    const int t  = threadIdx.x;
    const int bn = blockIdx.x * BN;
    const int bm = blockIdx.y * BM;

    constexpr int NTX = BN / TN;           // 16
    const int tx = t % NTX;
    const int ty = t / NTX;

    constexpr int NA = (BM * BK) / (256 * 4);   // float4 loads per thread (A)
    constexpr int NW = (BN * BK) / (256 * 4);   // float4 loads per thread (W)

    const float* Ab = A + (size_t)bm * K;
    const float* Wb = W + (size_t)bn * K;

    float4 pa[NA], pw[NW];

    auto loadA = [&](int k0) {
        #pragma unroll
        for (int i = 0; i < NA; ++i) {
            const int idx = t + i * 256;
            const int row = idx >> 2;          // BK/4 = 4 float4s per row
            const int c4  = idx & 3;
            pa[i] = *reinterpret_cast<const float4*>(Ab + (size_t)row * K + k0 + c4 * 4);
        }
    };
    auto loadW = [&](int k0) {
        #pragma unroll
        for (int i = 0; i < NW; ++i) {
            const int idx = t + i * 256;
            const int row = idx >> 2;
            const int c4  = idx & 3;
            pw[i] = *reinterpret_cast<const float4*>(Wb + (size_t)row * K + k0 + c4 * 4);
        }
    };

    float acc[TM][TN];
    #pragma unroll
    for (int i = 0; i < TM; ++i)
        #pragma unroll
        for (int j = 0; j < TN; ++j) acc[i][j] = 0.0f;

    loadA(0); loadW(0);

    for (int k0 = 0; k0 < K; k0 += BK) {
        __syncthreads();                    // previous compute done reading LDS
        #pragma unroll
        for (int i = 0; i < NA; ++i) {
            const int idx = t + i * 256;
            const int row = idx >> 2;
            const int c4  = idx & 3;
            As[c4 * 4 + 0][row] = pa[i].x;
            As[c4 * 4 + 1][row] = pa[i].y;
            As[c4 * 4 + 2][row] = pa[i].z;
            As[c4 * 4 + 3][row] = pa[i].w;
        }
        #pragma unroll
        for (int i = 0; i < NW; ++i) {
            const int idx = t + i * 256;
            const int row = idx >> 2;
            const int c4  = idx & 3;
            Ws[c4 * 4 + 0][row] = pw[i].x;
            Ws[c4 * 4 + 1][row] = pw[i].y;
            Ws[c4 * 4 + 2][row] = pw[i].z;
            Ws[c4 * 4 + 3][row] = pw[i].w;
        }
        __syncthreads();
        if (k0 + BK < K) { loadA(k0 + BK); loadW(k0 + BK); }  // prefetch under compute

        #pragma unroll
        for (int kk = 0; kk < BK; ++kk) {
            float a[TM], bv[TN];
            #pragma unroll
            for (int i = 0; i < TM; i += 4) {
                const float4 f = *reinterpret_cast<const float4*>(&As[kk][ty * TM + i]);
                a[i] = f.x; a[i+1] = f.y; a[i+2] = f.z; a[i+3] = f.w;
            }
            #pragma unroll
            for (int j = 0; j < TN; j += 4) {
                const float4 f = *reinterpret_cast<const float4*>(&Ws[kk][tx * TN + j]);
                bv[j] = f.x; bv[j+1] = f.y; bv[j+2] = f.z; bv[j+3] = f.w;
            }
            #pragma unroll
            for (int i = 0; i < TM; ++i)
                #pragma unroll
                for (int j = 0; j < TN; ++j)
                    acc[i][j] = fmaf(a[i], bv[j], acc[i][j]);
        }
    }

    // epilogue
    float bvals[TN];
    #pragma unroll
    for (int j = 0; j < TN; ++j) bvals[j] = bias[bn + tx * TN + j];

    #pragma unroll
    for (int i = 0; i < TM; ++i) {
        const int m = bm + ty * TM + i;
        float* crow = C + (size_t)m * N + bn + tx * TN;
        const float* rrow = (EPI == 1) ? (Res + (size_t)m * N + bn + tx * TN) : nullptr;
        #pragma unroll
        for (int j = 0; j < TN; j += 4) {
            float4 o;
            float vv[4];
            #pragma unroll
            for (int jj = 0; jj < 4; ++jj) {
                float v = acc[i][j + jj] + bvals[j + jj];
                if (EPI == 2) v = 0.5f * v * (1.0f + erff(v * 0.70710678118654752f));
                vv[jj] = v;
            }
            if (EPI == 1) {
                const float4 r = *reinterpret_cast<const float4*>(rrow + j);
                vv[0] += r.x; vv[1] += r.y; vv[2] += r.z; vv[3] += r.w;
            }
            o.x = vv[0]; o.y = vv[1]; o.z = vv[2]; o.w = vv[3];
            *reinterpret_cast<float4*>(crow + j) = o;
        }
    }
}

// ---------------------------------------------------------------- Local attention
// window radius 4; qkv layout [B,S,3D]; q at +0, k at +512, v at +1024,
// head h occupies dims [h*64, h*64+64). ctx out: [B,S,D], d = h*64+dh.
__global__ __launch_bounds__(256)
void attn_kernel(const float* __restrict__ qkv, float* __restrict__ ctx)
{
    constexpr int RAD = 4;
    constexpr int TQ  = 64;
    constexpr int KROWS = TQ + 2 * RAD;   // 72
    constexpr int LDK = DHH + 4;          // 68

    __shared__ float Ks[KROWS][LDK];
    __shared__ float Vs[KROWS][LDK];

    const int t  = threadIdx.x;
    const int qt = blockIdx.x;       // 0..31
    const int b  = blockIdx.y;       // 0..3
    const int h  = blockIdx.z;       // 0..7
    const int q0 = qt * TQ;
    const float* base = qkv + ((size_t)b * SS) * QKV_N + h * DHH;

    for (int idx = t; idx < KROWS * (DHH / 4); idx += 256) {
        const int row = idx >> 4;
        const int c4  = idx & 15;
        const int gr  = q0 - RAD + row;
        float4 kv = make_float4(0.f, 0.f, 0.f, 0.f);
        float4 vv = kv;
        if (gr >= 0 && gr < SS) {
            const float* p = base + (size_t)gr * QKV_N;
            kv = *reinterpret_cast<const float4*>(p + DD      + c4 * 4);
            vv = *reinterpret_cast<const float4*>(p + 2 * DD  + c4 * 4);
        }
        *reinterpret_cast<float4*>(&Ks[row][c4 * 4]) = kv;
        *reinterpret_cast<float4*>(&Vs[row][c4 * 4]) = vv;
    }
    __syncthreads();

    const int qi   = t >> 2;          // 0..63 query within tile
    const int quad = t & 3;           // 16 dims per lane
    const int gq   = q0 + qi;
    const int d0   = quad * 16;

    const float* qp = base + (size_t)gq * QKV_N + d0;
    float4 q[4];
    #pragma unroll
    for (int i = 0; i < 4; ++i) q[i] = *reinterpret_cast<const float4*>(qp + i * 4);

    float s[2 * RAD + 1];
    #pragma unroll
    for (int j = 0; j < 2 * RAD + 1; ++j) {
        const float* kr = &Ks[qi + j][d0];
        float p = 0.f;
        #pragma unroll
        for (int i = 0; i < 4; ++i) {
            const float4 k4 = *reinterpret_cast<const float4*>(kr + i * 4);
            p += q[i].x * k4.x + q[i].y * k4.y + q[i].z * k4.z + q[i].w * k4.w;
        }
        p += __shfl_xor(p, 1);
        p += __shfl_xor(p, 2);
        const int gk = gq + j - RAD;
        s[j] = (gk >= 0 && gk < SS) ? p * 0.125f : -INFINITY;
    }
    float mx = s[0];
    #pragma unroll
    for (int j = 1; j < 9; ++j) mx = fmaxf(mx, s[j]);
    float pr[9]; float l = 0.f;
    #pragma unroll
    for (int j = 0; j < 9; ++j) { pr[j] = __expf(s[j] - mx); l += pr[j]; }
    const float inv = 1.0f / l;

    float o[16];
    #pragma unroll
    for (int i = 0; i < 16; ++i) o[i] = 0.f;
    #pragma unroll
    for (int j = 0; j < 9; ++j) {
        const float pj = pr[j] * inv;
        const float* vr = &Vs[qi + j][d0];
        #pragma unroll
        for (int i = 0; i < 16; i += 4) {
            const float4 v4 = *reinterpret_cast<const float4*>(vr + i);
            o[i]     = fmaf(pj, v4.x, o[i]);
            o[i + 1] = fmaf(pj, v4.y, o[i + 1]);
            o[i + 2] = fmaf(pj, v4.z, o[i + 2]);
            o[i + 3] = fmaf(pj, v4.w, o[i + 3]);
        }
    }
    float* op = ctx + ((size_t)(b * SS + gq)) * DD + h * DHH + d0;
    #pragma unroll
    for (int i = 0; i < 16; i += 4)
        *reinterpret_cast<float4*>(op + i) = make_float4(o[i], o[i+1], o[i+2], o[i+3]);
}

// ---------------------------------------------------------------- launch
extern "C" void kernel_launch(void* const* d_in, const int* in_sizes, int n_in,
                              void* d_out, int out_size, void* d_ws, size_t ws_size,
                              hipStream_t stream)
{
    const float* x       = (const float*)d_in[0];
    const float* w_in    = (const float*)d_in[1];
    const float* b_in    = (const float*)d_in[2];
    const float* w_out   = (const float*)d_in[3];
    const float* b_out   = (const float*)d_in[4];
    const float* w_ff1   = (const float*)d_in[5];
    const float* b_ff1   = (const float*)d_in[6];
    const float* w_ff2   = (const float*)d_in[7];
    const float* b_ff2   = (const float*)d_in[8];
    const float* ln1_g   = (const float*)d_in[9];
    const float* ln1_b   = (const float*)d_in[10];
    const float* ln2_g   = (const float*)d_in[11];
    const float* ln2_b   = (const float*)d_in[12];
    float* out = (float*)d_out;

    // workspace layout (floats)
    float* h_buf = (float*)d_ws;                       // [8192,512] LN out (reused for ln2)
    float* x1    = h_buf + (size_t)MM * DD;            // [8192,512] x + attn_out
    float* ctxb  = x1    + (size_t)MM * DD;            // [8192,512] attention context
    float* big   = ctxb  + (size_t)MM * DD;            // [8192,2048] qkv (1536) then ff hidden (2048)

    // 1. LN1
    ln_kernel<<<MM, 128, 0, stream>>>(x, ln1_g, ln1_b, h_buf);

    // 2. QKV projection: [8192,512] @ [1536,512]^T -> [8192,1536]
    sgemm_kernel<128, 128, 8, 8, 0><<<dim3(QKV_N / 128, MM / 128), 256, 0, stream>>>(
        h_buf, w_in, b_in, nullptr, big, MM, QKV_N, DD);

    // 3. local attention
    attn_kernel<<<dim3(SS / 64, BB, HH), 256, 0, stream>>>(big, ctxb);

    // 4. out projection + residual: x1 = x + ctx @ out_w^T + b
    sgemm_kernel<64, 128, 4, 8, 1><<<dim3(DD / 128, MM / 64), 256, 0, stream>>>(
        ctxb, w_out, b_out, x, x1, MM, DD, DD);

    // 5. LN2
    ln_kernel<<<MM, 128, 0, stream>>>(x1, ln2_g, ln2_b, h_buf);

    // 6. FF1 + exact GELU: [8192,512] @ [2048,512]^T -> [8192,2048]
    sgemm_kernel<128, 128, 8, 8, 2><<<dim3(DFF / 128, MM / 128), 256, 0, stream>>>(
        h_buf, w_ff1, b_ff1, nullptr, big, MM, DFF, DD);

    // 7. FF2 + residual: out = x1 + ffh @ ff_w2^T + b
    sgemm_kernel<64, 128, 4, 8, 1><<<dim3(DD / 128, MM / 64), 256, 0, stream>>>(
        big, w_ff2, b_ff2, x1, out, MM, DD, DFF);
}

// Round 4
// 242.584 us; speedup vs baseline: 2.9219x; 2.9219x over previous
//
#include <hip/hip_runtime.h>
#include <hip/hip_bf16.h>
#include <math.h>

// Problem constants
#define BB 4
#define SS 2048
#define DD 512
#define HH 8
#define DHH 64
#define DFF 2048
#define MM (BB*SS)          // 8192 rows
#define QKV_N (3*DD)        // 1536

typedef float  f32x4  __attribute__((ext_vector_type(4)));
typedef __bf16 bf16x8 __attribute__((ext_vector_type(8)));
typedef unsigned short us8 __attribute__((ext_vector_type(8)));
typedef unsigned short us4 __attribute__((ext_vector_type(4)));

// ---- bf16 helpers (RNE, finite inputs) ----
__device__ __forceinline__ unsigned short f2bf(float v) {
    unsigned int u = __float_as_uint(v);
    unsigned int r = (u + 0x7fffu + ((u >> 16) & 1u)) >> 16;
    return (unsigned short)r;
}
__device__ __forceinline__ float bf2f(unsigned short h) {
    return __uint_as_float(((unsigned int)h) << 16);
}

__device__ __forceinline__ f32x4 mfma_bf16(us8 a, us8 b, f32x4 c) {
    return __builtin_amdgcn_mfma_f32_16x16x32_bf16(
        __builtin_bit_cast(bf16x8, a), __builtin_bit_cast(bf16x8, b), c, 0, 0, 0);
}

__device__ __forceinline__ void gload_lds16(const void* gsrc, void* ldst) {
    __builtin_amdgcn_global_load_lds(
        (const __attribute__((address_space(1))) void*)gsrc,
        (__attribute__((address_space(3))) void*)ldst, 16, 0, 0);
}

// Split-bf16 global layout: per row of K elements -> K/32 blocks of 128B:
// [32 x bf16 hi][32 x bf16 lo]. ushort index: row*2K + (k/32)*64 + (k%32); lo at +32.

// ---------------------------------------------------------------- LayerNorm -> split bf16
__global__ __launch_bounds__(128)
void ln_kernel(const float* __restrict__ x, const float* __restrict__ g,
               const float* __restrict__ beta, unsigned short* __restrict__ outp)
{
    const int row = blockIdx.x;
    const int t = threadIdx.x;               // 128 threads, 4 floats each
    const float4 v = reinterpret_cast<const float4*>(x + (size_t)row * DD)[t];

    float s  = v.x + v.y + v.z + v.w;
    float s2 = v.x*v.x + v.y*v.y + v.z*v.z + v.w*v.w;
    #pragma unroll
    for (int off = 32; off >= 1; off >>= 1) {
        s  += __shfl_xor(s,  off);
        s2 += __shfl_xor(s2, off);
    }
    __shared__ float red[2][2];
    const int lane = t & 63, wid = t >> 6;
    if (lane == 0) { red[wid][0] = s; red[wid][1] = s2; }
    __syncthreads();
    const float ts  = red[0][0] + red[1][0];
    const float ts2 = red[0][1] + red[1][1];
    const float mu  = ts * (1.0f / DD);
    const float var = ts2 * (1.0f / DD) - mu * mu;
    const float rs  = rsqrtf(var + 1e-5f);

    const float4 gv = reinterpret_cast<const float4*>(g)[t];
    const float4 bv = reinterpret_cast<const float4*>(beta)[t];
    float vals[4];
    vals[0] = (v.x - mu) * rs * gv.x + bv.x;
    vals[1] = (v.y - mu) * rs * gv.y + bv.y;
    vals[2] = (v.z - mu) * rs * gv.z + bv.z;
    vals[3] = (v.w - mu) * rs * gv.w + bv.w;

    us4 hv, lv;
    #pragma unroll
    for (int i = 0; i < 4; ++i) {
        hv[i] = f2bf(vals[i]);
        lv[i] = f2bf(vals[i] - bf2f(hv[i]));
    }
    const int k = t * 4;
    size_t o = (size_t)row * 1024 + (size_t)(k >> 5) * 64 + (k & 31);
    *reinterpret_cast<us4*>(outp + o)      = hv;
    *reinterpret_cast<us4*>(outp + o + 32) = lv;
}

// ---------------------------------------------------------------- fp32 -> split bf16 (weights)
__global__ __launch_bounds__(256)
void conv_split(const float* __restrict__ in, unsigned short* __restrict__ outp,
                int total /* R*K/8 */, int K)
{
    const int gid = blockIdx.x * 256 + threadIdx.x;
    if (gid >= total) return;
    const int cpr = K >> 3;
    const int r = gid / cpr;
    const int k0 = (gid - r * cpr) * 8;
    const float* p = in + (size_t)r * K + k0;
    us8 h, l;
    #pragma unroll
    for (int i = 0; i < 8; ++i) {
        float v = p[i];
        h[i] = f2bf(v);
        l[i] = f2bf(v - bf2f(h[i]));
    }
    size_t o = (size_t)r * (size_t)(K * 2) + (size_t)(k0 >> 5) * 64 + (k0 & 31);
    *reinterpret_cast<us8*>(outp + o)      = h;
    *reinterpret_cast<us8*>(outp + o + 32) = l;
}

// ---------------------------------------------------------------- split-bf16 MFMA GEMM
// C[m,n] = sum_k A[m,k]*W[n,k] + bias[n]; A,W in split layout.
// EPI: 0 = bias -> fp32 Cf; 1 = bias + Res -> fp32 Cf; 2 = bias + GELU -> split Cs
template<int EPI>
__global__ __launch_bounds__(256, 2)
void gemm_split(const unsigned short* __restrict__ Ax, const unsigned short* __restrict__ Wx,
                const float* __restrict__ bias, const float* __restrict__ Res,
                float* __restrict__ Cf, unsigned short* __restrict__ Cs,
                int M, int N, int K)
{
    // LDS: [dbuf][A/W][128 rows x 128B]; physical chunk slot q_phys = q_log ^ (row & 7)
    __shared__ unsigned short smem[2][2][8192];
    const int tid  = threadIdx.x;
    const int wave = tid >> 6, lane = tid & 63;
    const int wm = wave >> 1, wn = wave & 1;
    const int bn = blockIdx.x * 128, bm = blockIdx.y * 128;
    const int K2  = K * 2;
    const int nkb = K >> 5;

    const int lr = lane & 15;     // fragment row
    const int kc = lane >> 4;     // k-chunk 0..3

    // LDS ushort offsets of hi fragments (lo = ^32)
    int aoff[4], woff[4];
    #pragma unroll
    for (int m = 0; m < 4; ++m) {
        int ra = wm * 64 + m * 16 + lr;
        aoff[m] = ra * 64 + ((kc ^ (ra & 7)) * 8);
        int rw = wn * 64 + m * 16 + lr;
        woff[m] = rw * 64 + ((kc ^ (rw & 7)) * 8);
    }

    // staging: lane covers LDS slot (row8 = lane>>3, slot = lane&7); source logical chunk = slot ^ row8
    const int srow = lane >> 3;
    const int sq   = (lane & 7) ^ srow;

    f32x4 acc[4][4];
    #pragma unroll
    for (int m = 0; m < 4; ++m)
        #pragma unroll
        for (int n = 0; n < 4; ++n)
            acc[m][n] = (f32x4){0.f, 0.f, 0.f, 0.f};

    auto stage = [&](int buf, int kb) {
        #pragma unroll
        for (int i = 0; i < 4; ++i) {
            const int rr = wave * 32 + i * 8 + srow;
            const unsigned short* asrc = Ax + (size_t)(bm + rr) * K2 + (size_t)kb * 64 + sq * 8;
            gload_lds16(asrc, &smem[buf][0][wave * 2048 + i * 512]);
            const unsigned short* wsrc = Wx + (size_t)(bn + rr) * K2 + (size_t)kb * 64 + sq * 8;
            gload_lds16(wsrc, &smem[buf][1][wave * 2048 + i * 512]);
        }
    };

    stage(0, 0);
    int buf = 0;
    for (int kb = 0; kb < nkb; ++kb) {
        __syncthreads();                       // stage(buf) drained; prev reads done
        if (kb + 1 < nkb) stage(buf ^ 1, kb + 1);

        const unsigned short* As = smem[buf][0];
        const unsigned short* Ws = smem[buf][1];
        us8 ah[4], al[4], wh[4], wl[4];
        #pragma unroll
        for (int m = 0; m < 4; ++m) {
            ah[m] = *reinterpret_cast<const us8*>(As + aoff[m]);
            al[m] = *reinterpret_cast<const us8*>(As + (aoff[m] ^ 32));
            wh[m] = *reinterpret_cast<const us8*>(Ws + woff[m]);
            wl[m] = *reinterpret_cast<const us8*>(Ws + (woff[m] ^ 32));
        }
        #pragma unroll
        for (int m = 0; m < 4; ++m)
            #pragma unroll
            for (int n = 0; n < 4; ++n) {
                acc[m][n] = mfma_bf16(ah[m], wh[n], acc[m][n]);
                acc[m][n] = mfma_bf16(ah[m], wl[n], acc[m][n]);
                acc[m][n] = mfma_bf16(al[m], wh[n], acc[m][n]);
            }
        buf ^= 1;
    }

    // epilogue; C/D layout: col = lane&15, row = (lane>>4)*4 + reg
    float bvn[4];
    #pragma unroll
    for (int n = 0; n < 4; ++n) bvn[n] = bias[bn + wn * 64 + n * 16 + lr];

    #pragma unroll
    for (int m = 0; m < 4; ++m) {
        #pragma unroll
        for (int j = 0; j < 4; ++j) {
            const int row = bm + wm * 64 + m * 16 + kc * 4 + j;
            #pragma unroll
            for (int n = 0; n < 4; ++n) {
                const int col = bn + wn * 64 + n * 16 + lr;
                float v = acc[m][n][j] + bvn[n];
                if (EPI == 1) v += Res[(size_t)row * N + col];
                if (EPI == 2) {
                    v = 0.5f * v * (1.0f + erff(v * 0.70710678118654752f));
                    unsigned short h = f2bf(v);
                    unsigned short l = f2bf(v - bf2f(h));
                    size_t o = (size_t)row * (size_t)(N * 2) + (size_t)(col >> 5) * 64 + (col & 31);
                    Cs[o]      = h;
                    Cs[o + 32] = l;
                } else {
                    Cf[(size_t)row * N + col] = v;
                }
            }
        }
    }
}

// ---------------------------------------------------------------- Local attention (fp32 in, split out)
__global__ __launch_bounds__(256)
void attn_kernel(const float* __restrict__ qkv, unsigned short* __restrict__ ctx)
{
    constexpr int RAD = 4;
    constexpr int TQ  = 64;
    constexpr int KROWS = TQ + 2 * RAD;   // 72
    constexpr int LDK = DHH + 4;          // 68

    __shared__ float Ks[KROWS][LDK];
    __shared__ float Vs[KROWS][LDK];

    const int t  = threadIdx.x;
    const int qt = blockIdx.x;
    const int b  = blockIdx.y;
    const int h  = blockIdx.z;
    const int q0 = qt * TQ;
    const float* base = qkv + ((size_t)b * SS) * QKV_N + h * DHH;

    for (int idx = t; idx < KROWS * (DHH / 4); idx += 256) {
        const int row = idx >> 4;
        const int c4  = idx & 15;
        const int gr  = q0 - RAD + row;
        float4 kv = make_float4(0.f, 0.f, 0.f, 0.f);
        float4 vv = kv;
        if (gr >= 0 && gr < SS) {
            const float* p = base + (size_t)gr * QKV_N;
            kv = *reinterpret_cast<const float4*>(p + DD     + c4 * 4);
            vv = *reinterpret_cast<const float4*>(p + 2 * DD + c4 * 4);
        }
        *reinterpret_cast<float4*>(&Ks[row][c4 * 4]) = kv;
        *reinterpret_cast<float4*>(&Vs[row][c4 * 4]) = vv;
    }
    __syncthreads();

    const int qi   = t >> 2;
    const int quad = t & 3;
    const int gq   = q0 + qi;
    const int d0   = quad * 16;

    const float* qp = base + (size_t)gq * QKV_N + d0;
    float4 q[4];
    #pragma unroll
    for (int i = 0; i < 4; ++i) q[i] = *reinterpret_cast<const float4*>(qp + i * 4);

    float s[9];
    #pragma unroll
    for (int j = 0; j < 9; ++j) {
        const float* kr = &Ks[qi + j][d0];
        float p = 0.f;
        #pragma unroll
        for (int i = 0; i < 4; ++i) {
            const float4 k4 = *reinterpret_cast<const float4*>(kr + i * 4);
            p += q[i].x * k4.x + q[i].y * k4.y + q[i].z * k4.z + q[i].w * k4.w;
        }
        p += __shfl_xor(p, 1);
        p += __shfl_xor(p, 2);
        const int gk = gq + j - RAD;
        s[j] = (gk >= 0 && gk < SS) ? p * 0.125f : -INFINITY;
    }
    float mx = s[0];
    #pragma unroll
    for (int j = 1; j < 9; ++j) mx = fmaxf(mx, s[j]);
    float pr[9]; float l = 0.f;
    #pragma unroll
    for (int j = 0; j < 9; ++j) { pr[j] = __expf(s[j] - mx); l += pr[j]; }
    const float inv = 1.0f / l;

    float o[16];
    #pragma unroll
    for (int i = 0; i < 16; ++i) o[i] = 0.f;
    #pragma unroll
    for (int j = 0; j < 9; ++j) {
        const float pj = pr[j] * inv;
        const float* vr = &Vs[qi + j][d0];
        #pragma unroll
        for (int i = 0; i < 16; i += 4) {
            const float4 v4 = *reinterpret_cast<const float4*>(vr + i);
            o[i]     = fmaf(pj, v4.x, o[i]);
            o[i + 1] = fmaf(pj, v4.y, o[i + 1]);
            o[i + 2] = fmaf(pj, v4.z, o[i + 2]);
            o[i + 3] = fmaf(pj, v4.w, o[i + 3]);
        }
    }
    // write split-bf16 ctx: row = b*SS+gq, cols col0..col0+15
    const int col0 = h * DHH + d0;
    unsigned short* op = ctx + (size_t)(b * SS + gq) * 1024
                       + (size_t)(col0 >> 5) * 64 + (col0 & 31);
    us8 h0, h1, l0, l1;
    #pragma unroll
    for (int i = 0; i < 8; ++i) {
        h0[i] = f2bf(o[i]);      l0[i] = f2bf(o[i]     - bf2f(h0[i]));
        h1[i] = f2bf(o[8 + i]);  l1[i] = f2bf(o[8 + i] - bf2f(h1[i]));
    }
    *reinterpret_cast<us8*>(op)      = h0;
    *reinterpret_cast<us8*>(op + 8)  = h1;
    *reinterpret_cast<us8*>(op + 32) = l0;
    *reinterpret_cast<us8*>(op + 40) = l1;
}

// ---------------------------------------------------------------- launch
extern "C" void kernel_launch(void* const* d_in, const int* in_sizes, int n_in,
                              void* d_out, int out_size, void* d_ws, size_t ws_size,
                              hipStream_t stream)
{
    const float* x     = (const float*)d_in[0];
    const float* w_in  = (const float*)d_in[1];
    const float* b_in  = (const float*)d_in[2];
    const float* w_out = (const float*)d_in[3];
    const float* b_out = (const float*)d_in[4];
    const float* w_ff1 = (const float*)d_in[5];
    const float* b_ff1 = (const float*)d_in[6];
    const float* w_ff2 = (const float*)d_in[7];
    const float* b_ff2 = (const float*)d_in[8];
    const float* ln1_g = (const float*)d_in[9];
    const float* ln1_b = (const float*)d_in[10];
    const float* ln2_g = (const float*)d_in[11];
    const float* ln2_b = (const float*)d_in[12];
    float* out = (float*)d_out;

    // workspace layout (bytes):
    // [0,16M)    lnq   split [8192][512]    (LN1 out, reused for LN2 out)
    // [16M,32M)  x1    fp32  [8192][512]
    // [32M,48M)  ctxs  split [8192][512]    \ overlaid later by
    // [48M,96M)  qkv   fp32  [8192][1536]   / ffh split [8192][2048] (67MB)
    // [96M+3M..] weights split
    char* ws = (char*)d_ws;
    unsigned short* lnq  = (unsigned short*)ws;
    float*          x1   = (float*)(ws + 16777216);
    unsigned short* ctxs = (unsigned short*)(ws + 2 * 16777216);
    float*          qkv  = (float*)(ws + 3 * 16777216);
    unsigned short* ffh  = (unsigned short*)(ws + 2 * 16777216);   // 67,108,864 B
    unsigned short* wqs  = (unsigned short*)(ws + 2 * 16777216 + 67108864);
    unsigned short* wos  = wqs + (size_t)1536 * 1024;
    unsigned short* w1s  = wos + (size_t)512 * 1024;
    unsigned short* w2s  = w1s + (size_t)2048 * 1024;

    // weight conversions (every launch; deterministic)
    conv_split<<<(1536 * 512 / 8 + 255) / 256, 256, 0, stream>>>(w_in,  wqs, 1536 * 512 / 8, 512);
    conv_split<<<( 512 * 512 / 8 + 255) / 256, 256, 0, stream>>>(w_out, wos,  512 * 512 / 8, 512);
    conv_split<<<(2048 * 512 / 8 + 255) / 256, 256, 0, stream>>>(w_ff1, w1s, 2048 * 512 / 8, 512);
    conv_split<<<( 512 * 2048 / 8 + 255) / 256, 256, 0, stream>>>(w_ff2, w2s, 512 * 2048 / 8, 2048);

    // 1. LN1 -> split
    ln_kernel<<<MM, 128, 0, stream>>>(x, ln1_g, ln1_b, lnq);

    // 2. QKV: [8192,512]x[1536,512]^T -> fp32 qkv
    gemm_split<0><<<dim3(QKV_N / 128, MM / 128), 256, 0, stream>>>(
        lnq, wqs, b_in, nullptr, qkv, nullptr, MM, QKV_N, 512);

    // 3. local attention -> split ctx
    attn_kernel<<<dim3(SS / 64, BB, HH), 256, 0, stream>>>(qkv, ctxs);

    // 4. out-proj + residual: x1 = x + ctx @ out_w^T + b
    gemm_split<1><<<dim3(DD / 128, MM / 128), 256, 0, stream>>>(
        ctxs, wos, b_out, x, x1, nullptr, MM, DD, 512);

    // 5. LN2 -> split
    ln_kernel<<<MM, 128, 0, stream>>>(x1, ln2_g, ln2_b, lnq);

    // 6. FF1 + GELU -> split ffh
    gemm_split<2><<<dim3(DFF / 128, MM / 128), 256, 0, stream>>>(
        lnq, w1s, b_ff1, nullptr, nullptr, ffh, MM, DFF, 512);

    // 7. FF2 + residual: out = x1 + ffh @ ff_w2^T + b
    gemm_split<1><<<dim3(DD / 128, MM / 128), 256, 0, stream>>>(
        ffh, w2s, b_ff2, x1, out, nullptr, MM, DD, 2048);
}

// Round 5
// 233.266 us; speedup vs baseline: 3.0386x; 1.0399x over previous
//
#include <hip/hip_runtime.h>
#include <hip/hip_bf16.h>
#include <math.h>

// Problem constants
#define BB 4
#define SS 2048
#define DD 512
#define HH 8
#define DHH 64
#define DFF 2048
#define MM (BB*SS)          // 8192 rows
#define QKV_N (3*DD)        // 1536

typedef float  f32x4  __attribute__((ext_vector_type(4)));
typedef __bf16 bf16x8 __attribute__((ext_vector_type(8)));
typedef unsigned short us8 __attribute__((ext_vector_type(8)));
typedef unsigned short us4 __attribute__((ext_vector_type(4)));

// ---- bf16 helpers (RNE, finite inputs) ----
__device__ __forceinline__ unsigned short f2bf(float v) {
    unsigned int u = __float_as_uint(v);
    unsigned int r = (u + 0x7fffu + ((u >> 16) & 1u)) >> 16;
    return (unsigned short)r;
}
__device__ __forceinline__ float bf2f(unsigned short h) {
    return __uint_as_float(((unsigned int)h) << 16);
}

__device__ __forceinline__ f32x4 mfma_bf16(us8 a, us8 b, f32x4 c) {
    return __builtin_amdgcn_mfma_f32_16x16x32_bf16(
        __builtin_bit_cast(bf16x8, a), __builtin_bit_cast(bf16x8, b), c, 0, 0, 0);
}

__device__ __forceinline__ void gload_lds16(const void* gsrc, void* ldst) {
    __builtin_amdgcn_global_load_lds(
        (const __attribute__((address_space(1))) void*)gsrc,
        (__attribute__((address_space(3))) void*)ldst, 16, 0, 0);
}

// Split-bf16 global layout: per row of K elements -> K/32 blocks of 128B:
// [32 x bf16 hi][32 x bf16 lo]. ushort index: row*2K + (k/32)*64 + (k%32); lo at +32.

// ---------------------------------------------------------------- LayerNorm -> split bf16
__global__ __launch_bounds__(128)
void ln_kernel(const float* __restrict__ x, const float* __restrict__ g,
               const float* __restrict__ beta, unsigned short* __restrict__ outp)
{
    const int row = blockIdx.x;
    const int t = threadIdx.x;               // 128 threads, 4 floats each
    const float4 v = reinterpret_cast<const float4*>(x + (size_t)row * DD)[t];

    float s  = v.x + v.y + v.z + v.w;
    float s2 = v.x*v.x + v.y*v.y + v.z*v.z + v.w*v.w;
    #pragma unroll
    for (int off = 32; off >= 1; off >>= 1) {
        s  += __shfl_xor(s,  off);
        s2 += __shfl_xor(s2, off);
    }
    __shared__ float red[2][2];
    const int lane = t & 63, wid = t >> 6;
    if (lane == 0) { red[wid][0] = s; red[wid][1] = s2; }
    __syncthreads();
    const float ts  = red[0][0] + red[1][0];
    const float ts2 = red[0][1] + red[1][1];
    const float mu  = ts * (1.0f / DD);
    const float var = ts2 * (1.0f / DD) - mu * mu;
    const float rs  = rsqrtf(var + 1e-5f);

    const float4 gv = reinterpret_cast<const float4*>(g)[t];
    const float4 bv = reinterpret_cast<const float4*>(beta)[t];
    float vals[4];
    vals[0] = (v.x - mu) * rs * gv.x + bv.x;
    vals[1] = (v.y - mu) * rs * gv.y + bv.y;
    vals[2] = (v.z - mu) * rs * gv.z + bv.z;
    vals[3] = (v.w - mu) * rs * gv.w + bv.w;

    us4 hv, lv;
    #pragma unroll
    for (int i = 0; i < 4; ++i) {
        hv[i] = f2bf(vals[i]);
        lv[i] = f2bf(vals[i] - bf2f(hv[i]));
    }
    const int k = t * 4;
    size_t o = (size_t)row * 1024 + (size_t)(k >> 5) * 64 + (k & 31);
    *reinterpret_cast<us4*>(outp + o)      = hv;
    *reinterpret_cast<us4*>(outp + o + 32) = lv;
}

// ---------------------------------------------------------------- fp32 -> split bf16 (weights)
__global__ __launch_bounds__(256)
void conv_split(const float* __restrict__ in, unsigned short* __restrict__ outp,
                int total /* R*K/8 */, int K)
{
    const int gid = blockIdx.x * 256 + threadIdx.x;
    if (gid >= total) return;
    const int cpr = K >> 3;
    const int r = gid / cpr;
    const int k0 = (gid - r * cpr) * 8;
    const float* p = in + (size_t)r * K + k0;
    us8 h, l;
    #pragma unroll
    for (int i = 0; i < 8; ++i) {
        float v = p[i];
        h[i] = f2bf(v);
        l[i] = f2bf(v - bf2f(h[i]));
    }
    size_t o = (size_t)r * (size_t)(K * 2) + (size_t)(k0 >> 5) * 64 + (k0 & 31);
    *reinterpret_cast<us8*>(outp + o)      = h;
    *reinterpret_cast<us8*>(outp + o + 32) = l;
}

// ---------------------------------------------------------------- 8-wave 256-row MFMA GEMM
// Counted-vmcnt pipeline (T3/T4): loads stay 2 K-tiles in flight, never drained to 0
// in the main loop. BM=256 fixed, BN template (256 or 128), BK=32 elements.
// EPI: 0 = bias -> fp32 Cf; 2 = bias+GELU -> split Cs; 3 = partial fp32 (slab z -> Cf/Cf1)
template<int BN, int EPI>
__global__ __launch_bounds__(512, 2)
void gemm8p(const unsigned short* __restrict__ Ax, const unsigned short* __restrict__ Wx,
            const float* __restrict__ bias,
            float* __restrict__ Cf, float* __restrict__ Cf1, unsigned short* __restrict__ Cs,
            int Astride2, int Wstride2, int N, int nkt)
{
    constexpr int NF   = BN / 64;          // n-frags per wave (4 or 2)
    constexpr int LPT  = 4 + BN / 64;      // gload_lds per thread per K-tile (8 or 6)
    constexpr int AUSH = 256 * 64;
    constexpr int BUSH = BN * 64;
    __shared__ unsigned short smem[2][AUSH + BUSH];

    const int tid  = threadIdx.x;
    const int wave = tid >> 6, lane = tid & 63;
    const int wm = wave >> 2, wn = wave & 3;
    const int lr = lane & 15, kc = lane >> 4;
    const int xk = (kc ^ (lr & 7)) * 8;            // swizzled chunk offset (ush)
    const int bm  = blockIdx.y * 256;
    const int bnn = blockIdx.x * BN;
    const int kb0 = blockIdx.z * nkt;

    // staging: thread covers LDS (row = i*64 + tid>>3, slot = tid&7); src chunk = slot ^ (row&7)
    const int srow   = tid >> 3;
    const int schunk = ((tid & 7) ^ (srow & 7)) * 8;

    int aof[8];
    #pragma unroll
    for (int m = 0; m < 8; ++m) aof[m] = (wm * 128 + m * 16 + lr) * 64 + xk;
    int bof[NF];
    #pragma unroll
    for (int n = 0; n < NF; ++n) bof[n] = AUSH + (wn * NF * 16 + n * 16 + lr) * 64 + xk;

    auto stage = [&](int buf, int kb) {
        #pragma unroll
        for (int i = 0; i < 4; ++i) {
            const int r = i * 64 + srow;
            gload_lds16(Ax + (size_t)(bm + r) * Astride2 + (size_t)kb * 64 + schunk,
                        &smem[buf][(i * 64 + (wave << 3)) * 64]);
        }
        #pragma unroll
        for (int i = 0; i < BN / 64; ++i) {
            const int r = i * 64 + srow;
            gload_lds16(Wx + (size_t)(bnn + r) * Wstride2 + (size_t)kb * 64 + schunk,
                        &smem[buf][AUSH + (i * 64 + (wave << 3)) * 64]);
        }
    };

    f32x4 acc[8][NF];
    #pragma unroll
    for (int m = 0; m < 8; ++m)
        #pragma unroll
        for (int n = 0; n < NF; ++n) acc[m][n] = (f32x4){0.f, 0.f, 0.f, 0.f};

    stage(0, kb0); stage(1, kb0 + 1);
    if constexpr (LPT == 8) asm volatile("s_waitcnt vmcnt(8)" ::: "memory");
    else                    asm volatile("s_waitcnt vmcnt(6)" ::: "memory");
    __builtin_amdgcn_s_barrier();

    for (int t = 0; t < nkt; ++t) {
        const unsigned short* S = smem[t & 1];
        us8 bh[NF], bl[NF], ah[4], al[4];
        #pragma unroll
        for (int n = 0; n < NF; ++n) {
            bh[n] = *reinterpret_cast<const us8*>(S + bof[n]);
            bl[n] = *reinterpret_cast<const us8*>(S + (bof[n] ^ 32));
        }
        #pragma unroll
        for (int m = 0; m < 4; ++m) {
            ah[m] = *reinterpret_cast<const us8*>(S + aof[m]);
            al[m] = *reinterpret_cast<const us8*>(S + (aof[m] ^ 32));
        }
        __builtin_amdgcn_s_setprio(1);
        #pragma unroll
        for (int m = 0; m < 4; ++m)
            #pragma unroll
            for (int n = 0; n < NF; ++n) {
                acc[m][n] = mfma_bf16(ah[m], bh[n], acc[m][n]);
                acc[m][n] = mfma_bf16(ah[m], bl[n], acc[m][n]);
                acc[m][n] = mfma_bf16(al[m], bh[n], acc[m][n]);
            }
        __builtin_amdgcn_s_setprio(0);
        #pragma unroll
        for (int m = 0; m < 4; ++m) {
            ah[m] = *reinterpret_cast<const us8*>(S + aof[4 + m]);
            al[m] = *reinterpret_cast<const us8*>(S + (aof[4 + m] ^ 32));
        }
        __builtin_amdgcn_s_setprio(1);
        #pragma unroll
        for (int m = 0; m < 4; ++m)
            #pragma unroll
            for (int n = 0; n < NF; ++n) {
                acc[4 + m][n] = mfma_bf16(ah[m], bh[n], acc[4 + m][n]);
                acc[4 + m][n] = mfma_bf16(ah[m], bl[n], acc[4 + m][n]);
                acc[4 + m][n] = mfma_bf16(al[m], bh[n], acc[4 + m][n]);
            }
        __builtin_amdgcn_s_setprio(0);

        // all this wave's LDS reads of buf (t&1) complete before any wave overwrites it
        asm volatile("s_waitcnt lgkmcnt(0)" ::: "memory");
        __builtin_amdgcn_sched_barrier(0);
        __builtin_amdgcn_s_barrier();

        if (t + 2 < nkt) stage(t & 1, kb0 + t + 2);
        if (t + 1 < nkt) {
            if (t + 2 < nkt) {
                if constexpr (LPT == 8) asm volatile("s_waitcnt vmcnt(8)" ::: "memory");
                else                    asm volatile("s_waitcnt vmcnt(6)" ::: "memory");
            } else {
                asm volatile("s_waitcnt vmcnt(0)" ::: "memory");
            }
        }
        __builtin_amdgcn_s_barrier();
    }

    // epilogue; C/D layout: col = lane&15, row = (lane>>4)*4 + reg
    #pragma unroll
    for (int m = 0; m < 8; ++m) {
        #pragma unroll
        for (int j = 0; j < 4; ++j) {
            const int row = bm + wm * 128 + m * 16 + kc * 4 + j;
            #pragma unroll
            for (int n = 0; n < NF; ++n) {
                const int col = bnn + wn * NF * 16 + n * 16 + lr;
                float v = acc[m][n][j];
                if constexpr (EPI == 0) {
                    Cf[(size_t)row * N + col] = v + bias[col];
                } else if constexpr (EPI == 2) {
                    v += bias[col];
                    v = 0.5f * v * (1.0f + erff(v * 0.70710678118654752f));
                    unsigned short h = f2bf(v);
                    unsigned short l = f2bf(v - bf2f(h));
                    size_t o = (size_t)row * (size_t)(N * 2) + (size_t)(col >> 5) * 64 + (col & 31);
                    Cs[o]      = h;
                    Cs[o + 32] = l;
                } else {
                    float* dst = blockIdx.z ? Cf1 : Cf;
                    dst[(size_t)row * N + col] = v;
                }
            }
        }
    }
}

// ---------------------------------------------------------------- FF2 split-K reduce
// out = x1 + bias + p0 + p1
__global__ __launch_bounds__(256)
void ff2_reduce(const float* __restrict__ p0, const float* __restrict__ p1,
                const float* __restrict__ x1, const float* __restrict__ bias,
                float* __restrict__ out)
{
    const int i = blockIdx.x * 256 + threadIdx.x;       // float4 index
    const float4 a = reinterpret_cast<const float4*>(p0)[i];
    const float4 b = reinterpret_cast<const float4*>(p1)[i];
    const float4 r = reinterpret_cast<const float4*>(x1)[i];
    const float4 bv = reinterpret_cast<const float4*>(bias)[i & 127];
    float4 o;
    o.x = r.x + a.x + b.x + bv.x;
    o.y = r.y + a.y + b.y + bv.y;
    o.z = r.z + a.z + b.z + bv.z;
    o.w = r.w + a.w + b.w + bv.w;
    reinterpret_cast<float4*>(out)[i] = o;
}

// ---------------------------------------------------------------- 128x128 split GEMM (out-proj)
// EPI 1 = bias + residual -> fp32
template<int EPI>
__global__ __launch_bounds__(256, 2)
void gemm_split(const unsigned short* __restrict__ Ax, const unsigned short* __restrict__ Wx,
                const float* __restrict__ bias, const float* __restrict__ Res,
                float* __restrict__ Cf, unsigned short* __restrict__ Cs,
                int M, int N, int K)
{
    __shared__ unsigned short smem[2][2][8192];
    const int tid  = threadIdx.x;
    const int wave = tid >> 6, lane = tid & 63;
    const int wm = wave >> 1, wn = wave & 1;
    const int bn = blockIdx.x * 128, bm = blockIdx.y * 128;
    const int K2  = K * 2;
    const int nkb = K >> 5;

    const int lr = lane & 15;
    const int kc = lane >> 4;

    int aoff[4], woff[4];
    #pragma unroll
    for (int m = 0; m < 4; ++m) {
        int ra = wm * 64 + m * 16 + lr;
        aoff[m] = ra * 64 + ((kc ^ (ra & 7)) * 8);
        int rw = wn * 64 + m * 16 + lr;
        woff[m] = rw * 64 + ((kc ^ (rw & 7)) * 8);
    }

    const int srow = lane >> 3;
    const int sq   = (lane & 7) ^ srow;

    f32x4 acc[4][4];
    #pragma unroll
    for (int i = 0; i < 4; ++i)
        #pragma unroll
        for (int j = 0; j < 4; ++j) acc[i][j] = (f32x4){0.f, 0.f, 0.f, 0.f};

    auto stage = [&](int buf, int kb) {
        #pragma unroll
        for (int i = 0; i < 4; ++i) {
            const int rr = wave * 32 + i * 8 + srow;
            gload_lds16(Ax + (size_t)(bm + rr) * K2 + (size_t)kb * 64 + sq * 8,
                        &smem[buf][0][wave * 2048 + i * 512]);
            gload_lds16(Wx + (size_t)(bn + rr) * K2 + (size_t)kb * 64 + sq * 8,
                        &smem[buf][1][wave * 2048 + i * 512]);
        }
    };

    stage(0, 0);
    int buf = 0;
    for (int kb = 0; kb < nkb; ++kb) {
        __syncthreads();
        if (kb + 1 < nkb) stage(buf ^ 1, kb + 1);

        const unsigned short* As = smem[buf][0];
        const unsigned short* Ws = smem[buf][1];
        us8 ah[4], al[4], wh[4], wl[4];
        #pragma unroll
        for (int m = 0; m < 4; ++m) {
            ah[m] = *reinterpret_cast<const us8*>(As + aoff[m]);
            al[m] = *reinterpret_cast<const us8*>(As + (aoff[m] ^ 32));
            wh[m] = *reinterpret_cast<const us8*>(Ws + woff[m]);
            wl[m] = *reinterpret_cast<const us8*>(Ws + (woff[m] ^ 32));
        }
        #pragma unroll
        for (int m = 0; m < 4; ++m)
            #pragma unroll
            for (int n = 0; n < 4; ++n) {
                acc[m][n] = mfma_bf16(ah[m], wh[n], acc[m][n]);
                acc[m][n] = mfma_bf16(ah[m], wl[n], acc[m][n]);
                acc[m][n] = mfma_bf16(al[m], wh[n], acc[m][n]);
            }
        buf ^= 1;
    }

    float bvn[4];
    #pragma unroll
    for (int n = 0; n < 4; ++n) bvn[n] = bias[bn + wn * 64 + n * 16 + lr];

    #pragma unroll
    for (int m = 0; m < 4; ++m) {
        #pragma unroll
        for (int j = 0; j < 4; ++j) {
            const int row = bm + wm * 64 + m * 16 + kc * 4 + j;
            #pragma unroll
            for (int n = 0; n < 4; ++n) {
                const int col = bn + wn * 64 + n * 16 + lr;
                float v = acc[m][n][j] + bvn[n];
                if (EPI == 1) v += Res[(size_t)row * N + col];
                Cf[(size_t)row * N + col] = v;
            }
        }
    }
}

// ---------------------------------------------------------------- Local attention (fp32 in, split out)
__global__ __launch_bounds__(256)
void attn_kernel(const float* __restrict__ qkv, unsigned short* __restrict__ ctx)
{
    constexpr int RAD = 4;
    constexpr int TQ  = 64;
    constexpr int KROWS = TQ + 2 * RAD;   // 72
    constexpr int LDK = DHH + 4;          // 68

    __shared__ float Ks[KROWS][LDK];
    __shared__ float Vs[KROWS][LDK];

    const int t  = threadIdx.x;
    const int qt = blockIdx.x;
    const int b  = blockIdx.y;
    const int h  = blockIdx.z;
    const int q0 = qt * TQ;
    const float* base = qkv + ((size_t)b * SS) * QKV_N + h * DHH;

    for (int idx = t; idx < KROWS * (DHH / 4); idx += 256) {
        const int row = idx >> 4;
        const int c4  = idx & 15;
        const int gr  = q0 - RAD + row;
        float4 kv = make_float4(0.f, 0.f, 0.f, 0.f);
        float4 vv = kv;
        if (gr >= 0 && gr < SS) {
            const float* p = base + (size_t)gr * QKV_N;
            kv = *reinterpret_cast<const float4*>(p + DD     + c4 * 4);
            vv = *reinterpret_cast<const float4*>(p + 2 * DD + c4 * 4);
        }
        *reinterpret_cast<float4*>(&Ks[row][c4 * 4]) = kv;
        *reinterpret_cast<float4*>(&Vs[row][c4 * 4]) = vv;
    }
    __syncthreads();

    const int qi   = t >> 2;
    const int quad = t & 3;
    const int gq   = q0 + qi;
    const int d0   = quad * 16;

    const float* qp = base + (size_t)gq * QKV_N + d0;
    float4 q[4];
    #pragma unroll
    for (int i = 0; i < 4; ++i) q[i] = *reinterpret_cast<const float4*>(qp + i * 4);

    float s[9];
    #pragma unroll
    for (int j = 0; j < 9; ++j) {
        const float* kr = &Ks[qi + j][d0];
        float p = 0.f;
        #pragma unroll
        for (int i = 0; i < 4; ++i) {
            const float4 k4 = *reinterpret_cast<const float4*>(kr + i * 4);
            p += q[i].x * k4.x + q[i].y * k4.y + q[i].z * k4.z + q[i].w * k4.w;
        }
        p += __shfl_xor(p, 1);
        p += __shfl_xor(p, 2);
        const int gk = gq + j - RAD;
        s[j] = (gk >= 0 && gk < SS) ? p * 0.125f : -INFINITY;
    }
    float mx = s[0];
    #pragma unroll
    for (int j = 1; j < 9; ++j) mx = fmaxf(mx, s[j]);
    float pr[9]; float l = 0.f;
    #pragma unroll
    for (int j = 0; j < 9; ++j) { pr[j] = __expf(s[j] - mx); l += pr[j]; }
    const float inv = 1.0f / l;

    float o[16];
    #pragma unroll
    for (int i = 0; i < 16; ++i) o[i] = 0.f;
    #pragma unroll
    for (int j = 0; j < 9; ++j) {
        const float pj = pr[j] * inv;
        const float* vr = &Vs[qi + j][d0];
        #pragma unroll
        for (int i = 0; i < 16; i += 4) {
            const float4 v4 = *reinterpret_cast<const float4*>(vr + i);
            o[i]     = fmaf(pj, v4.x, o[i]);
            o[i + 1] = fmaf(pj, v4.y, o[i + 1]);
            o[i + 2] = fmaf(pj, v4.z, o[i + 2]);
            o[i + 3] = fmaf(pj, v4.w, o[i + 3]);
        }
    }
    const int col0 = h * DHH + d0;
    unsigned short* op = ctx + (size_t)(b * SS + gq) * 1024
                       + (size_t)(col0 >> 5) * 64 + (col0 & 31);
    us8 h0, h1, l0, l1;
    #pragma unroll
    for (int i = 0; i < 8; ++i) {
        h0[i] = f2bf(o[i]);      l0[i] = f2bf(o[i]     - bf2f(h0[i]));
        h1[i] = f2bf(o[8 + i]);  l1[i] = f2bf(o[8 + i] - bf2f(h1[i]));
    }
    *reinterpret_cast<us8*>(op)      = h0;
    *reinterpret_cast<us8*>(op + 8)  = h1;
    *reinterpret_cast<us8*>(op + 32) = l0;
    *reinterpret_cast<us8*>(op + 40) = l1;
}

// ---------------------------------------------------------------- launch
extern "C" void kernel_launch(void* const* d_in, const int* in_sizes, int n_in,
                              void* d_out, int out_size, void* d_ws, size_t ws_size,
                              hipStream_t stream)
{
    const float* x     = (const float*)d_in[0];
    const float* w_in  = (const float*)d_in[1];
    const float* b_in  = (const float*)d_in[2];
    const float* w_out = (const float*)d_in[3];
    const float* b_out = (const float*)d_in[4];
    const float* w_ff1 = (const float*)d_in[5];
    const float* b_ff1 = (const float*)d_in[6];
    const float* w_ff2 = (const float*)d_in[7];
    const float* b_ff2 = (const float*)d_in[8];
    const float* ln1_g = (const float*)d_in[9];
    const float* ln1_b = (const float*)d_in[10];
    const float* ln2_g = (const float*)d_in[11];
    const float* ln2_b = (const float*)d_in[12];
    float* out = (float*)d_out;

    // workspace layout (bytes):
    // [0,16M)    lnq   split [8192][512]    (LN out; reused as FF2 partial1 after FF1)
    // [16M,32M)  x1    fp32  [8192][512]
    // [32M,48M)  ctxs  split [8192][512]    \ overlaid later by
    // [48M,96M)  qkv   fp32  [8192][1536]   / ffh split [8192][2048] (67MB)
    // [99.1M..]  weights split
    char* ws = (char*)d_ws;
    unsigned short* lnq  = (unsigned short*)ws;
    float*          x1   = (float*)(ws + 16777216);
    unsigned short* ctxs = (unsigned short*)(ws + 2 * 16777216);
    float*          qkv  = (float*)(ws + 3 * 16777216);
    unsigned short* ffh  = (unsigned short*)(ws + 2 * 16777216);   // 67,108,864 B
    unsigned short* wqs  = (unsigned short*)(ws + 2 * 16777216 + 67108864);
    unsigned short* wos  = wqs + (size_t)1536 * 1024;
    unsigned short* w1s  = wos + (size_t)512 * 1024;
    unsigned short* w2s  = w1s + (size_t)2048 * 1024;
    float*          p1   = (float*)ws;                             // FF2 partial 1 (lnq dead)

    // weight conversions
    conv_split<<<(1536 * 512 / 8 + 255) / 256, 256, 0, stream>>>(w_in,  wqs, 1536 * 512 / 8, 512);
    conv_split<<<( 512 * 512 / 8 + 255) / 256, 256, 0, stream>>>(w_out, wos,  512 * 512 / 8, 512);
    conv_split<<<(2048 * 512 / 8 + 255) / 256, 256, 0, stream>>>(w_ff1, w1s, 2048 * 512 / 8, 512);
    conv_split<<<( 512 * 2048 / 8 + 255) / 256, 256, 0, stream>>>(w_ff2, w2s, 512 * 2048 / 8, 2048);

    // 1. LN1 -> split
    ln_kernel<<<MM, 128, 0, stream>>>(x, ln1_g, ln1_b, lnq);

    // 2. QKV: [8192,512]x[1536,512]^T -> fp32 qkv (8-wave counted-vmcnt kernel)
    gemm8p<256, 0><<<dim3(QKV_N / 256, MM / 256, 1), 512, 0, stream>>>(
        lnq, wqs, b_in, qkv, nullptr, nullptr, 1024, 1024, QKV_N, 16);

    // 3. local attention -> split ctx
    attn_kernel<<<dim3(SS / 64, BB, HH), 256, 0, stream>>>(qkv, ctxs);

    // 4. out-proj + residual: x1 = x + ctx @ out_w^T + b  (128^2 kernel)
    gemm_split<1><<<dim3(DD / 128, MM / 128), 256, 0, stream>>>(
        ctxs, wos, b_out, x, x1, nullptr, MM, DD, 512);

    // 5. LN2 -> split
    ln_kernel<<<MM, 128, 0, stream>>>(x1, ln2_g, ln2_b, lnq);

    // 6. FF1 + GELU -> split ffh
    gemm8p<256, 2><<<dim3(DFF / 256, MM / 256, 1), 512, 0, stream>>>(
        lnq, w1s, b_ff1, nullptr, nullptr, ffh, 1024, 1024, DFF, 16);

    // 7. FF2 split-K=2: slab partials -> d_out (slab0) and p1 (slab1)
    gemm8p<128, 3><<<dim3(DD / 128, MM / 256, 2), 512, 0, stream>>>(
        ffh, w2s, nullptr, out, p1, nullptr, 4096, 4096, DD, 32);

    // 8. reduce: out = x1 + b_ff2 + p0 + p1
    ff2_reduce<<<(MM * DD / 4) / 256, 256, 0, stream>>>(out, p1, x1, b_ff2, out);
}

// Round 6
// 229.907 us; speedup vs baseline: 3.0830x; 1.0146x over previous
//
#include <hip/hip_runtime.h>
#include <hip/hip_bf16.h>
#include <math.h>

// Problem constants
#define BB 4
#define SS 2048
#define DD 512
#define HH 8
#define DHH 64
#define DFF 2048
#define MM (BB*SS)          // 8192 rows
#define QKV_N (3*DD)        // 1536

typedef float  f32x4  __attribute__((ext_vector_type(4)));
typedef __bf16 bf16x8 __attribute__((ext_vector_type(8)));
typedef unsigned short us8 __attribute__((ext_vector_type(8)));
typedef unsigned short us4 __attribute__((ext_vector_type(4)));

// ---- bf16 helpers (RNE, finite inputs) ----
__device__ __forceinline__ unsigned short f2bf(float v) {
    unsigned int u = __float_as_uint(v);
    unsigned int r = (u + 0x7fffu + ((u >> 16) & 1u)) >> 16;
    return (unsigned short)r;
}
__device__ __forceinline__ float bf2f(unsigned short h) {
    return __uint_as_float(((unsigned int)h) << 16);
}

__device__ __forceinline__ f32x4 mfma_bf16(us8 a, us8 b, f32x4 c) {
    return __builtin_amdgcn_mfma_f32_16x16x32_bf16(
        __builtin_bit_cast(bf16x8, a), __builtin_bit_cast(bf16x8, b), c, 0, 0, 0);
}

__device__ __forceinline__ void gload_lds16(const void* gsrc, void* ldst) {
    __builtin_amdgcn_global_load_lds(
        (const __attribute__((address_space(1))) void*)gsrc,
        (__attribute__((address_space(3))) void*)ldst, 16, 0, 0);
}

#define VMC(n) asm volatile("s_waitcnt vmcnt(" #n ")" ::: "memory")

// Split-bf16 global layout: per row of K elements -> K/32 blocks of 128B:
// [32 x bf16 hi][32 x bf16 lo]. ushort index: row*2K + (k/32)*64 + (k%32); lo at +32.

// ---------------------------------------------------------------- LayerNorm -> split bf16
__global__ __launch_bounds__(128)
void ln_kernel(const float* __restrict__ x, const float* __restrict__ g,
               const float* __restrict__ beta, unsigned short* __restrict__ outp)
{
    const int row = blockIdx.x;
    const int t = threadIdx.x;               // 128 threads, 4 floats each
    const float4 v = reinterpret_cast<const float4*>(x + (size_t)row * DD)[t];

    float s  = v.x + v.y + v.z + v.w;
    float s2 = v.x*v.x + v.y*v.y + v.z*v.z + v.w*v.w;
    #pragma unroll
    for (int off = 32; off >= 1; off >>= 1) {
        s  += __shfl_xor(s,  off);
        s2 += __shfl_xor(s2, off);
    }
    __shared__ float red[2][2];
    const int lane = t & 63, wid = t >> 6;
    if (lane == 0) { red[wid][0] = s; red[wid][1] = s2; }
    __syncthreads();
    const float ts  = red[0][0] + red[1][0];
    const float ts2 = red[0][1] + red[1][1];
    const float mu  = ts * (1.0f / DD);
    const float var = ts2 * (1.0f / DD) - mu * mu;
    const float rs  = rsqrtf(var + 1e-5f);

    const float4 gv = reinterpret_cast<const float4*>(g)[t];
    const float4 bv = reinterpret_cast<const float4*>(beta)[t];
    float vals[4];
    vals[0] = (v.x - mu) * rs * gv.x + bv.x;
    vals[1] = (v.y - mu) * rs * gv.y + bv.y;
    vals[2] = (v.z - mu) * rs * gv.z + bv.z;
    vals[3] = (v.w - mu) * rs * gv.w + bv.w;

    us4 hv, lv;
    #pragma unroll
    for (int i = 0; i < 4; ++i) {
        hv[i] = f2bf(vals[i]);
        lv[i] = f2bf(vals[i] - bf2f(hv[i]));
    }
    const int k = t * 4;
    size_t o = (size_t)row * 1024 + (size_t)(k >> 5) * 64 + (k & 31);
    *reinterpret_cast<us4*>(outp + o)      = hv;
    *reinterpret_cast<us4*>(outp + o + 32) = lv;
}

// ---------------------------------------------------------------- fp32 -> split bf16 (weights)
__global__ __launch_bounds__(256)
void conv_split(const float* __restrict__ in, unsigned short* __restrict__ outp,
                int total /* R*K/8 */, int K)
{
    const int gid = blockIdx.x * 256 + threadIdx.x;
    if (gid >= total) return;
    const int cpr = K >> 3;
    const int r = gid / cpr;
    const int k0 = (gid - r * cpr) * 8;
    const float* p = in + (size_t)r * K + k0;
    us8 h, l;
    #pragma unroll
    for (int i = 0; i < 8; ++i) {
        float v = p[i];
        h[i] = f2bf(v);
        l[i] = f2bf(v - bf2f(h[i]));
    }
    size_t o = (size_t)r * (size_t)(K * 2) + (size_t)(k0 >> 5) * 64 + (k0 & 31);
    *reinterpret_cast<us8*>(outp + o)      = h;
    *reinterpret_cast<us8*>(outp + o + 32) = l;
}

// ---------------------------------------------------------------- 4-phase fine-interleaved GEMM
// BM=256, BK=32 logical (128B/row split), 8 waves (2M x 4N). Per K-tile: 4 phases,
// each = {ds_reads | 2 stage issues -> barrier -> lgkmcnt(0) -> 24*NF/4 MFMA -> counted vmcnt -> barrier}.
// Slab staging: A slabs 0-3 (64 rows each), B slabs 0..NF-1. Tile t+2 stages into the
// buffer being read, targeting only slabs whose readers passed a barrier.
// EPI: 0 = bias -> fp32 Cf; 2 = bias+GELU -> split Cs; 3 = partial fp32 (slab z -> Cf/Cf1)
template<int BN, int EPI>
__global__ __launch_bounds__(512, 2)
void gemm4p(const unsigned short* __restrict__ Ax, const unsigned short* __restrict__ Wx,
            const float* __restrict__ bias,
            float* __restrict__ Cf, float* __restrict__ Cf1, unsigned short* __restrict__ Cs,
            int Astride2, int Wstride2, int N, int nkt)
{
    constexpr int NF   = BN / 64;          // n-frags per wave (4 or 2)
    constexpr int AUSH = 256 * 64;         // A tile ushorts
    __shared__ unsigned short smem[2][AUSH + BN * 64];

    const int tid  = threadIdx.x;
    const int wave = tid >> 6, lane = tid & 63;
    const int wm = wave >> 2, wn = wave & 3;
    const int lr = lane & 15, kc = lane >> 4;
    const int xk = (kc ^ (lr & 7)) * 8;            // swizzled chunk offset (ush)
    const int bm  = blockIdx.y * 256;
    const int bnn = blockIdx.x * BN;
    const int kb0 = blockIdx.z * nkt;

    const int srow   = tid >> 3;                   // 0..63 within slab
    const int schunk = ((tid & 7) ^ (srow & 7)) * 8;

    int aof[8];
    #pragma unroll
    for (int m = 0; m < 8; ++m) aof[m] = (wm * 128 + m * 16 + lr) * 64 + xk;
    int bof[NF];
    #pragma unroll
    for (int n = 0; n < NF; ++n) bof[n] = AUSH + (wn * (NF * 16) + n * 16 + lr) * 64 + xk;

    auto stA = [&](int tt, int s) {
        gload_lds16(Ax + (size_t)(bm + s * 64 + srow) * Astride2 + (size_t)(kb0 + tt) * 64 + schunk,
                    &smem[tt & 1][s * 4096 + (wave << 9)]);
    };
    auto stB = [&](int tt, int s) {
        gload_lds16(Wx + (size_t)(bnn + s * 64 + srow) * Wstride2 + (size_t)(kb0 + tt) * 64 + schunk,
                    &smem[tt & 1][AUSH + s * 4096 + (wave << 9)]);
    };

    f32x4 acc[8][NF];
    #pragma unroll
    for (int m = 0; m < 8; ++m)
        #pragma unroll
        for (int n = 0; n < NF; ++n) acc[m][n] = (f32x4){0.f, 0.f, 0.f, 0.f};

    // Prologue: issue stream matching steady-state ordering.
    stB(0, 0); stB(0, 1);
    if constexpr (NF == 4) { stB(0, 2); stB(0, 3); }
    stA(0, 0); stA(0, 2);
    stA(0, 1); stA(0, 3);
    stB(1, 0); stB(1, 1);
    if constexpr (NF == 4) { stB(1, 2); stB(1, 3); }
    stA(1, 0); stA(1, 2);
    if constexpr (NF == 4) { VMC(8); } else { VMC(6); }
    __builtin_amdgcn_s_barrier();
    __builtin_amdgcn_sched_barrier(0);

// one phase: read A frags MP,MP+1 (hi+lo), issue STAGE, barrier, drain LDS, MFMA, WAITC, barrier
#define PHASE(MP, STAGE, WAITC)                                                   \
    {                                                                             \
        us8 ah0 = *reinterpret_cast<const us8*>(S + aof[MP]);                     \
        us8 al0 = *reinterpret_cast<const us8*>(S + (aof[MP] ^ 32));              \
        us8 ah1 = *reinterpret_cast<const us8*>(S + aof[MP + 1]);                 \
        us8 al1 = *reinterpret_cast<const us8*>(S + (aof[MP + 1] ^ 32));          \
        STAGE;                                                                    \
        __builtin_amdgcn_s_barrier();                                             \
        asm volatile("s_waitcnt lgkmcnt(0)" ::: "memory");                        \
        __builtin_amdgcn_sched_barrier(0);                                        \
        __builtin_amdgcn_s_setprio(1);                                            \
        _Pragma("unroll")                                                         \
        for (int n = 0; n < NF; ++n) {                                            \
            acc[MP][n]     = mfma_bf16(ah0, bh[n], acc[MP][n]);                   \
            acc[MP][n]     = mfma_bf16(ah0, bl[n], acc[MP][n]);                   \
            acc[MP][n]     = mfma_bf16(al0, bh[n], acc[MP][n]);                   \
            acc[MP + 1][n] = mfma_bf16(ah1, bh[n], acc[MP + 1][n]);               \
            acc[MP + 1][n] = mfma_bf16(ah1, bl[n], acc[MP + 1][n]);               \
            acc[MP + 1][n] = mfma_bf16(al1, bh[n], acc[MP + 1][n]);               \
        }                                                                         \
        __builtin_amdgcn_s_setprio(0);                                            \
        __builtin_amdgcn_sched_barrier(0);                                        \
        WAITC;                                                                    \
        __builtin_amdgcn_s_barrier();                                             \
        __builtin_amdgcn_sched_barrier(0);                                        \
    }

    for (int t = 0; t < nkt; ++t) {
        const unsigned short* S = smem[t & 1];
        // B fragments for this tile (live across all 4 phases)
        us8 bh[NF], bl[NF];
        #pragma unroll
        for (int n = 0; n < NF; ++n) {
            bh[n] = *reinterpret_cast<const us8*>(S + bof[n]);
            bl[n] = *reinterpret_cast<const us8*>(S + (bof[n] ^ 32));
        }

        // phi0: m0,m1 | stage A1,A3 of t+1 (other buffer; its A1/A3 readers done last tile)
        PHASE(0,
              { if (t + 1 < nkt) { stA(t + 1, 1); stA(t + 1, 3); } },
              { })

        // phi1: m2,m3 | stage B0,B1 of t+2 (same buffer; B readers done at phi0)
        //        end-wait: arrival of A1/A3(t) needed by phi2
        PHASE(2,
              { if (t + 2 < nkt) { stB(t + 2, 0); stB(t + 2, 1); } },
              {
                  if constexpr (NF == 4) {
                      if (t + 2 < nkt)       { VMC(10); }
                      else if (t + 2 == nkt) { VMC(8);  }
                      else                   { VMC(0);  }
                  } else {
                      if (t + 2 < nkt)       { VMC(8);  }
                      else if (t + 2 == nkt) { VMC(6);  }
                      else                   { VMC(0);  }
                  }
              })

        // phi2: m4,m5 | stage B2,B3 (NF=4) or A0,A2 (NF=2) of t+2
        PHASE(4,
              {
                  if (t + 2 < nkt) {
                      if constexpr (NF == 4) { stB(t + 2, 2); stB(t + 2, 3); }
                      else                   { stA(t + 2, 0); stA(t + 2, 2); }
                  }
              },
              { })

        // phi3: m6,m7 | stage A0,A2 of t+2 (NF=4; A0/A2 readers done at phi1)
        //        end-wait: arrival of B(t+1),A0/A2(t+1) needed by next phi0
        PHASE(6,
              {
                  if constexpr (NF == 4) {
                      if (t + 2 < nkt) { stA(t + 2, 0); stA(t + 2, 2); }
                  }
              },
              {
                  if (t + 1 < nkt) {
                      if constexpr (NF == 4) {
                          if (t + 2 < nkt) { VMC(8); } else { VMC(2); }
                      } else {
                          if (t + 2 < nkt) { VMC(6); } else { VMC(2); }
                      }
                  }
              })
    }
#undef PHASE

    // epilogue; C/D layout: col = lane&15, row = (lane>>4)*4 + reg
    #pragma unroll
    for (int m = 0; m < 8; ++m) {
        #pragma unroll
        for (int j = 0; j < 4; ++j) {
            const int row = bm + wm * 128 + m * 16 + kc * 4 + j;
            #pragma unroll
            for (int n = 0; n < NF; ++n) {
                const int col = bnn + wn * (NF * 16) + n * 16 + lr;
                float v = acc[m][n][j];
                if constexpr (EPI == 0) {
                    Cf[(size_t)row * N + col] = v + bias[col];
                } else if constexpr (EPI == 2) {
                    v += bias[col];
                    v = 0.5f * v * (1.0f + erff(v * 0.70710678118654752f));
                    unsigned short h = f2bf(v);
                    unsigned short l = f2bf(v - bf2f(h));
                    size_t o = (size_t)row * (size_t)(N * 2) + (size_t)(col >> 5) * 64 + (col & 31);
                    Cs[o]      = h;
                    Cs[o + 32] = l;
                } else {
                    float* dst = blockIdx.z ? Cf1 : Cf;
                    dst[(size_t)row * N + col] = v;
                }
            }
        }
    }
}

// ---------------------------------------------------------------- FF2 split-K reduce
// out = x1 + bias + p0 + p1
__global__ __launch_bounds__(256)
void ff2_reduce(const float* __restrict__ p0, const float* __restrict__ p1,
                const float* __restrict__ x1, const float* __restrict__ bias,
                float* __restrict__ out)
{
    const int i = blockIdx.x * 256 + threadIdx.x;       // float4 index
    const float4 a = reinterpret_cast<const float4*>(p0)[i];
    const float4 b = reinterpret_cast<const float4*>(p1)[i];
    const float4 r = reinterpret_cast<const float4*>(x1)[i];
    const float4 bv = reinterpret_cast<const float4*>(bias)[i & 127];
    float4 o;
    o.x = r.x + a.x + b.x + bv.x;
    o.y = r.y + a.y + b.y + bv.y;
    o.z = r.z + a.z + b.z + bv.z;
    o.w = r.w + a.w + b.w + bv.w;
    reinterpret_cast<float4*>(out)[i] = o;
}

// ---------------------------------------------------------------- 128x128 split GEMM (out-proj)
// EPI 1 = bias + residual -> fp32
template<int EPI>
__global__ __launch_bounds__(256, 2)
void gemm_split(const unsigned short* __restrict__ Ax, const unsigned short* __restrict__ Wx,
                const float* __restrict__ bias, const float* __restrict__ Res,
                float* __restrict__ Cf, unsigned short* __restrict__ Cs,
                int M, int N, int K)
{
    __shared__ unsigned short smem[2][2][8192];
    const int tid  = threadIdx.x;
    const int wave = tid >> 6, lane = tid & 63;
    const int wm = wave >> 1, wn = wave & 1;
    const int bn = blockIdx.x * 128, bm = blockIdx.y * 128;
    const int K2  = K * 2;
    const int nkb = K >> 5;

    const int lr = lane & 15;
    const int kc = lane >> 4;

    int aoff[4], woff[4];
    #pragma unroll
    for (int m = 0; m < 4; ++m) {
        int ra = wm * 64 + m * 16 + lr;
        aoff[m] = ra * 64 + ((kc ^ (ra & 7)) * 8);
        int rw = wn * 64 + m * 16 + lr;
        woff[m] = rw * 64 + ((kc ^ (rw & 7)) * 8);
    }

    const int srow = lane >> 3;
    const int sq   = (lane & 7) ^ srow;

    f32x4 acc[4][4];
    #pragma unroll
    for (int i = 0; i < 4; ++i)
        #pragma unroll
        for (int j = 0; j < 4; ++j) acc[i][j] = (f32x4){0.f, 0.f, 0.f, 0.f};

    auto stage = [&](int buf, int kb) {
        #pragma unroll
        for (int i = 0; i < 4; ++i) {
            const int rr = wave * 32 + i * 8 + srow;
            gload_lds16(Ax + (size_t)(bm + rr) * K2 + (size_t)kb * 64 + sq * 8,
                        &smem[buf][0][wave * 2048 + i * 512]);
            gload_lds16(Wx + (size_t)(bn + rr) * K2 + (size_t)kb * 64 + sq * 8,
                        &smem[buf][1][wave * 2048 + i * 512]);
        }
    };

    stage(0, 0);
    int buf = 0;
    for (int kb = 0; kb < nkb; ++kb) {
        __syncthreads();
        if (kb + 1 < nkb) stage(buf ^ 1, kb + 1);

        const unsigned short* As = smem[buf][0];
        const unsigned short* Ws = smem[buf][1];
        us8 ah[4], al[4], wh[4], wl[4];
        #pragma unroll
        for (int m = 0; m < 4; ++m) {
            ah[m] = *reinterpret_cast<const us8*>(As + aoff[m]);
            al[m] = *reinterpret_cast<const us8*>(As + (aoff[m] ^ 32));
            wh[m] = *reinterpret_cast<const us8*>(Ws + woff[m]);
            wl[m] = *reinterpret_cast<const us8*>(Ws + (woff[m] ^ 32));
        }
        #pragma unroll
        for (int m = 0; m < 4; ++m)
            #pragma unroll
            for (int n = 0; n < 4; ++n) {
                acc[m][n] = mfma_bf16(ah[m], wh[n], acc[m][n]);
                acc[m][n] = mfma_bf16(ah[m], wl[n], acc[m][n]);
                acc[m][n] = mfma_bf16(al[m], wh[n], acc[m][n]);
            }
        buf ^= 1;
    }

    float bvn[4];
    #pragma unroll
    for (int n = 0; n < 4; ++n) bvn[n] = bias[bn + wn * 64 + n * 16 + lr];

    #pragma unroll
    for (int m = 0; m < 4; ++m) {
        #pragma unroll
        for (int j = 0; j < 4; ++j) {
            const int row = bm + wm * 64 + m * 16 + kc * 4 + j;
            #pragma unroll
            for (int n = 0; n < 4; ++n) {
                const int col = bn + wn * 64 + n * 16 + lr;
                float v = acc[m][n][j] + bvn[n];
                if (EPI == 1) v += Res[(size_t)row * N + col];
                Cf[(size_t)row * N + col] = v;
            }
        }
    }
}

// ---------------------------------------------------------------- Local attention (fp32 in, split out)
__global__ __launch_bounds__(256)
void attn_kernel(const float* __restrict__ qkv, unsigned short* __restrict__ ctx)
{
    constexpr int RAD = 4;
    constexpr int TQ  = 64;
    constexpr int KROWS = TQ + 2 * RAD;   // 72
    constexpr int LDK = DHH + 4;          // 68

    __shared__ float Ks[KROWS][LDK];
    __shared__ float Vs[KROWS][LDK];

    const int t  = threadIdx.x;
    const int qt = blockIdx.x;
    const int b  = blockIdx.y;
    const int h  = blockIdx.z;
    const int q0 = qt * TQ;
    const float* base = qkv + ((size_t)b * SS) * QKV_N + h * DHH;

    for (int idx = t; idx < KROWS * (DHH / 4); idx += 256) {
        const int row = idx >> 4;
        const int c4  = idx & 15;
        const int gr  = q0 - RAD + row;
        float4 kv = make_float4(0.f, 0.f, 0.f, 0.f);
        float4 vv = kv;
        if (gr >= 0 && gr < SS) {
            const float* p = base + (size_t)gr * QKV_N;
            kv = *reinterpret_cast<const float4*>(p + DD     + c4 * 4);
            vv = *reinterpret_cast<const float4*>(p + 2 * DD + c4 * 4);
        }
        *reinterpret_cast<float4*>(&Ks[row][c4 * 4]) = kv;
        *reinterpret_cast<float4*>(&Vs[row][c4 * 4]) = vv;
    }
    __syncthreads();

    const int qi   = t >> 2;
    const int quad = t & 3;
    const int gq   = q0 + qi;
    const int d0   = quad * 16;

    const float* qp = base + (size_t)gq * QKV_N + d0;
    float4 q[4];
    #pragma unroll
    for (int i = 0; i < 4; ++i) q[i] = *reinterpret_cast<const float4*>(qp + i * 4);

    float s[9];
    #pragma unroll
    for (int j = 0; j < 9; ++j) {
        const float* kr = &Ks[qi + j][d0];
        float p = 0.f;
        #pragma unroll
        for (int i = 0; i < 4; ++i) {
            const float4 k4 = *reinterpret_cast<const float4*>(kr + i * 4);
            p += q[i].x * k4.x + q[i].y * k4.y + q[i].z * k4.z + q[i].w * k4.w;
        }
        p += __shfl_xor(p, 1);
        p += __shfl_xor(p, 2);
        const int gk = gq + j - RAD;
        s[j] = (gk >= 0 && gk < SS) ? p * 0.125f : -INFINITY;
    }
    float mx = s[0];
    #pragma unroll
    for (int j = 1; j < 9; ++j) mx = fmaxf(mx, s[j]);
    float pr[9]; float l = 0.f;
    #pragma unroll
    for (int j = 0; j < 9; ++j) { pr[j] = __expf(s[j] - mx); l += pr[j]; }
    const float inv = 1.0f / l;

    float o[16];
    #pragma unroll
    for (int i = 0; i < 16; ++i) o[i] = 0.f;
    #pragma unroll
    for (int j = 0; j < 9; ++j) {
        const float pj = pr[j] * inv;
        const float* vr = &Vs[qi + j][d0];
        #pragma unroll
        for (int i = 0; i < 16; i += 4) {
            const float4 v4 = *reinterpret_cast<const float4*>(vr + i);
            o[i]     = fmaf(pj, v4.x, o[i]);
            o[i + 1] = fmaf(pj, v4.y, o[i + 1]);
            o[i + 2] = fmaf(pj, v4.z, o[i + 2]);
            o[i + 3] = fmaf(pj, v4.w, o[i + 3]);
        }
    }
    const int col0 = h * DHH + d0;
    unsigned short* op = ctx + (size_t)(b * SS + gq) * 1024
                       + (size_t)(col0 >> 5) * 64 + (col0 & 31);
    us8 h0, h1, l0, l1;
    #pragma unroll
    for (int i = 0; i < 8; ++i) {
        h0[i] = f2bf(o[i]);      l0[i] = f2bf(o[i]     - bf2f(h0[i]));
        h1[i] = f2bf(o[8 + i]);  l1[i] = f2bf(o[8 + i] - bf2f(h1[i]));
    }
    *reinterpret_cast<us8*>(op)      = h0;
    *reinterpret_cast<us8*>(op + 8)  = h1;
    *reinterpret_cast<us8*>(op + 32) = l0;
    *reinterpret_cast<us8*>(op + 40) = l1;
}

// ---------------------------------------------------------------- launch
extern "C" void kernel_launch(void* const* d_in, const int* in_sizes, int n_in,
                              void* d_out, int out_size, void* d_ws, size_t ws_size,
                              hipStream_t stream)
{
    const float* x     = (const float*)d_in[0];
    const float* w_in  = (const float*)d_in[1];
    const float* b_in  = (const float*)d_in[2];
    const float* w_out = (const float*)d_in[3];
    const float* b_out = (const float*)d_in[4];
    const float* w_ff1 = (const float*)d_in[5];
    const float* b_ff1 = (const float*)d_in[6];
    const float* w_ff2 = (const float*)d_in[7];
    const float* b_ff2 = (const float*)d_in[8];
    const float* ln1_g = (const float*)d_in[9];
    const float* ln1_b = (const float*)d_in[10];
    const float* ln2_g = (const float*)d_in[11];
    const float* ln2_b = (const float*)d_in[12];
    float* out = (float*)d_out;

    // workspace layout (bytes):
    // [0,16M)    lnq   split [8192][512]    (LN out; reused as FF2 partial1 after FF1)
    // [16M,32M)  x1    fp32  [8192][512]
    // [32M,48M)  ctxs  split [8192][512]    \ overlaid later by
    // [48M,96M)  qkv   fp32  [8192][1536]   / ffh split [8192][2048] (67MB)
    // [99.1M..]  weights split
    char* ws = (char*)d_ws;
    unsigned short* lnq  = (unsigned short*)ws;
    float*          x1   = (float*)(ws + 16777216);
    unsigned short* ctxs = (unsigned short*)(ws + 2 * 16777216);
    float*          qkv  = (float*)(ws + 3 * 16777216);
    unsigned short* ffh  = (unsigned short*)(ws + 2 * 16777216);   // 67,108,864 B
    unsigned short* wqs  = (unsigned short*)(ws + 2 * 16777216 + 67108864);
    unsigned short* wos  = wqs + (size_t)1536 * 1024;
    unsigned short* w1s  = wos + (size_t)512 * 1024;
    unsigned short* w2s  = w1s + (size_t)2048 * 1024;
    float*          p1   = (float*)ws;                             // FF2 partial 1 (lnq dead)

    // weight conversions
    conv_split<<<(1536 * 512 / 8 + 255) / 256, 256, 0, stream>>>(w_in,  wqs, 1536 * 512 / 8, 512);
    conv_split<<<( 512 * 512 / 8 + 255) / 256, 256, 0, stream>>>(w_out, wos,  512 * 512 / 8, 512);
    conv_split<<<(2048 * 512 / 8 + 255) / 256, 256, 0, stream>>>(w_ff1, w1s, 2048 * 512 / 8, 512);
    conv_split<<<( 512 * 2048 / 8 + 255) / 256, 256, 0, stream>>>(w_ff2, w2s, 512 * 2048 / 8, 2048);

    // 1. LN1 -> split
    ln_kernel<<<MM, 128, 0, stream>>>(x, ln1_g, ln1_b, lnq);

    // 2. QKV: [8192,512]x[1536,512]^T -> fp32 qkv (4-phase kernel)
    gemm4p<256, 0><<<dim3(QKV_N / 256, MM / 256, 1), 512, 0, stream>>>(
        lnq, wqs, b_in, qkv, nullptr, nullptr, 1024, 1024, QKV_N, 16);

    // 3. local attention -> split ctx
    attn_kernel<<<dim3(SS / 64, BB, HH), 256, 0, stream>>>(qkv, ctxs);

    // 4. out-proj + residual: x1 = x + ctx @ out_w^T + b  (128^2 kernel)
    gemm_split<1><<<dim3(DD / 128, MM / 128), 256, 0, stream>>>(
        ctxs, wos, b_out, x, x1, nullptr, MM, DD, 512);

    // 5. LN2 -> split
    ln_kernel<<<MM, 128, 0, stream>>>(x1, ln2_g, ln2_b, lnq);

    // 6. FF1 + GELU -> split ffh (4-phase kernel)
    gemm4p<256, 2><<<dim3(DFF / 256, MM / 256, 1), 512, 0, stream>>>(
        lnq, w1s, b_ff1, nullptr, nullptr, ffh, 1024, 1024, DFF, 16);

    // 7. FF2 split-K=2: slab partials -> d_out (slab0) and p1 (slab1)
    gemm4p<128, 3><<<dim3(DD / 128, MM / 256, 2), 512, 0, stream>>>(
        ffh, w2s, nullptr, out, p1, nullptr, 4096, 4096, DD, 32);

    // 8. reduce: out = x1 + b_ff2 + p0 + p1
    ff2_reduce<<<(MM * DD / 4) / 256, 256, 0, stream>>>(out, p1, x1, b_ff2, out);
}

// Round 8
// 209.824 us; speedup vs baseline: 3.3781x; 1.0957x over previous
//
#include <hip/hip_runtime.h>
#include <hip/hip_bf16.h>
#include <math.h>

// Problem constants
#define BB 4
#define SS 2048
#define DD 512
#define HH 8
#define DHH 64
#define DFF 2048
#define MM (BB*SS)          // 8192 rows
#define QKV_N (3*DD)        // 1536

typedef float  f32x4  __attribute__((ext_vector_type(4)));
typedef __bf16 bf16x8 __attribute__((ext_vector_type(8)));
typedef unsigned short us8 __attribute__((ext_vector_type(8)));
typedef unsigned short us4 __attribute__((ext_vector_type(4)));

// ---- bf16 helpers (RNE, finite inputs) ----
__device__ __forceinline__ unsigned short f2bf(float v) {
    unsigned int u = __float_as_uint(v);
    unsigned int r = (u + 0x7fffu + ((u >> 16) & 1u)) >> 16;
    return (unsigned short)r;
}
__device__ __forceinline__ float bf2f(unsigned short h) {
    return __uint_as_float(((unsigned int)h) << 16);
}

__device__ __forceinline__ f32x4 mfma_bf16(us8 a, us8 b, f32x4 c) {
    return __builtin_amdgcn_mfma_f32_16x16x32_bf16(
        __builtin_bit_cast(bf16x8, a), __builtin_bit_cast(bf16x8, b), c, 0, 0, 0);
}

__device__ __forceinline__ void gload_lds16(const void* gsrc, void* ldst) {
    __builtin_amdgcn_global_load_lds(
        (const __attribute__((address_space(1))) void*)gsrc,
        (__attribute__((address_space(3))) void*)ldst, 16, 0, 0);
}

// Split-bf16 global layout: per row of K elements -> K/32 blocks of 128B:
// [32 x bf16 hi][32 x bf16 lo]. ushort index: row*2K + (k/32)*64 + (k%32); lo at +32.

// ---------------------------------------------------------------- LayerNorm -> split bf16
__global__ __launch_bounds__(128)
void ln_kernel(const float* __restrict__ x, const float* __restrict__ g,
               const float* __restrict__ beta, unsigned short* __restrict__ outp)
{
    const int row = blockIdx.x;
    const int t = threadIdx.x;               // 128 threads, 4 floats each
    const float4 v = reinterpret_cast<const float4*>(x + (size_t)row * DD)[t];

    float s  = v.x + v.y + v.z + v.w;
    float s2 = v.x*v.x + v.y*v.y + v.z*v.z + v.w*v.w;
    #pragma unroll
    for (int off = 32; off >= 1; off >>= 1) {
        s  += __shfl_xor(s,  off);
        s2 += __shfl_xor(s2, off);
    }
    __shared__ float red[2][2];
    const int lane = t & 63, wid = t >> 6;
    if (lane == 0) { red[wid][0] = s; red[wid][1] = s2; }
    __syncthreads();
    const float ts  = red[0][0] + red[1][0];
    const float ts2 = red[0][1] + red[1][1];
    const float mu  = ts * (1.0f / DD);
    const float var = ts2 * (1.0f / DD) - mu * mu;
    const float rs  = rsqrtf(var + 1e-5f);

    const float4 gv = reinterpret_cast<const float4*>(g)[t];
    const float4 bv = reinterpret_cast<const float4*>(beta)[t];
    float vals[4];
    vals[0] = (v.x - mu) * rs * gv.x + bv.x;
    vals[1] = (v.y - mu) * rs * gv.y + bv.y;
    vals[2] = (v.z - mu) * rs * gv.z + bv.z;
    vals[3] = (v.w - mu) * rs * gv.w + bv.w;

    us4 hv, lv;
    #pragma unroll
    for (int i = 0; i < 4; ++i) {
        hv[i] = f2bf(vals[i]);
        lv[i] = f2bf(vals[i] - bf2f(hv[i]));
    }
    const int k = t * 4;
    size_t o = (size_t)row * 1024 + (size_t)(k >> 5) * 64 + (k & 31);
    *reinterpret_cast<us4*>(outp + o)      = hv;
    *reinterpret_cast<us4*>(outp + o + 32) = lv;
}

// ---------------------------------------------------------------- fp32 -> split bf16 (weights)
__global__ __launch_bounds__(256)
void conv_split(const float* __restrict__ in, unsigned short* __restrict__ outp,
                int total /* R*K/8 */, int K)
{
    const int gid = blockIdx.x * 256 + threadIdx.x;
    if (gid >= total) return;
    const int cpr = K >> 3;
    const int r = gid / cpr;
    const int k0 = (gid - r * cpr) * 8;
    const float* p = in + (size_t)r * K + k0;
    us8 h, l;
    #pragma unroll
    for (int i = 0; i < 8; ++i) {
        float v = p[i];
        h[i] = f2bf(v);
        l[i] = f2bf(v - bf2f(h[i]));
    }
    size_t o = (size_t)r * (size_t)(K * 2) + (size_t)(k0 >> 5) * 64 + (k0 & 31);
    *reinterpret_cast<us8*>(outp + o)      = h;
    *reinterpret_cast<us8*>(outp + o + 32) = l;
}

// Fused conversion of w_in (1536x512) + w_out (512x512) + w_ff1 (2048x512)
// into one contiguous split region (rows 0..4095, K=512).
__global__ __launch_bounds__(256)
void conv3(const float* __restrict__ w_in, const float* __restrict__ w_out,
           const float* __restrict__ w_ff1, unsigned short* __restrict__ dst)
{
    const int gid = blockIdx.x * 256 + threadIdx.x;   // 4096 rows * 64 us8
    const int r  = gid >> 6;
    const int k0 = (gid & 63) * 8;
    const float* src = (r < 1536) ? w_in  + (size_t)r * 512 + k0
                     : (r < 2048) ? w_out + (size_t)(r - 1536) * 512 + k0
                                  : w_ff1 + (size_t)(r - 2048) * 512 + k0;
    us8 h, l;
    #pragma unroll
    for (int i = 0; i < 8; ++i) {
        float v = src[i];
        h[i] = f2bf(v);
        l[i] = f2bf(v - bf2f(h[i]));
    }
    size_t o = (size_t)r * 1024 + (size_t)(k0 >> 5) * 64 + (k0 & 31);
    *reinterpret_cast<us8*>(dst + o)      = h;
    *reinterpret_cast<us8*>(dst + o + 32) = l;
}

// ---------------------------------------------------------------- split-bf16 MFMA GEMM
// BM=128 fixed, BN in {128, 64}. 4 waves (2x2). 2-barrier double-buffered loop
// (proven m97-style structure). BN=128: 64KB LDS -> 2 blocks/CU. BN=64: 48KB -> 3/CU.
// XCD-aware bijective block swizzle (requires nwg % 8 == 0).
// EPI: 0 = bias -> fp32 Cf; 1 = bias + Res -> fp32 Cf; 2 = bias + GELU -> split Cs
template<int BN, int EPI>
__global__ __launch_bounds__(256, 2)
void gemm_tile(const unsigned short* __restrict__ Ax, const unsigned short* __restrict__ Wx,
               const float* __restrict__ bias, const float* __restrict__ Res,
               float* __restrict__ Cf, unsigned short* __restrict__ Cs,
               int N, int K)
{
    constexpr int NF   = BN / 32;          // n-frags per wave (4 or 2)
    constexpr int AUSH = 128 * 64;         // ushorts per A buffer
    constexpr int BUSH = BN * 64;
    __shared__ unsigned short smem[2][AUSH + BUSH];

    const int tid  = threadIdx.x;
    const int wave = tid >> 6, lane = tid & 63;
    const int wm = wave >> 1, wn = wave & 1;
    const int lr = lane & 15, kc = lane >> 4;

    // XCD swizzle: contiguous chunks of the flat grid per XCD
    const int nwg = gridDim.x * gridDim.y;
    int bid = blockIdx.y * gridDim.x + blockIdx.x;
    bid = (bid & 7) * (nwg >> 3) + (bid >> 3);
    const int bn = (bid % gridDim.x) * BN;
    const int bm = (bid / gridDim.x) * 128;

    const int K2  = K * 2;
    const int nkb = K >> 5;

    // LDS ushort offsets of hi fragments (lo = ^32); chunk swizzled by row&7
    int aoff[4], woff[NF];
    #pragma unroll
    for (int m = 0; m < 4; ++m) {
        const int ra = wm * 64 + m * 16 + lr;
        aoff[m] = ra * 64 + ((kc ^ (ra & 7)) * 8);
    }
    #pragma unroll
    for (int n = 0; n < NF; ++n) {
        const int rw = wn * (NF * 16) + n * 16 + lr;
        woff[n] = AUSH + rw * 64 + ((kc ^ (rw & 7)) * 8);
    }

    f32x4 acc[4][NF];
    #pragma unroll
    for (int i = 0; i < 4; ++i)
        #pragma unroll
        for (int j = 0; j < NF; ++j) acc[i][j] = (f32x4){0.f, 0.f, 0.f, 0.f};

    // staging: thread covers LDS linear off; row = off>>6, slot = (off>>3)&7,
    // source logical chunk = slot ^ (row&7)  (inverse of read swizzle)
    auto stage = [&](int buf, int kb) {
        #pragma unroll
        for (int j = 0; j < 4; ++j) {
            const int off = j * 2048 + tid * 8;
            const int row = off >> 6;
            const int q   = ((off >> 3) & 7) ^ (row & 7);
            gload_lds16(Ax + (size_t)(bm + row) * K2 + (size_t)kb * 64 + q * 8,
                        &smem[buf][off]);
        }
        #pragma unroll
        for (int j = 0; j < BN / 32; ++j) {
            const int off = j * 2048 + tid * 8;
            const int row = off >> 6;
            const int q   = ((off >> 3) & 7) ^ (row & 7);
            gload_lds16(Wx + (size_t)(bn + row) * K2 + (size_t)kb * 64 + q * 8,
                        &smem[buf][AUSH + off]);
        }
    };

    stage(0, 0);
    int buf = 0;
    for (int kb = 0; kb < nkb; ++kb) {
        __syncthreads();                       // stage(buf) drained; prev reads done
        if (kb + 1 < nkb) stage(buf ^ 1, kb + 1);

        const unsigned short* S = smem[buf];
        us8 ah[4], al[4], wh[NF], wl[NF];
        #pragma unroll
        for (int m = 0; m < 4; ++m) {
            ah[m] = *reinterpret_cast<const us8*>(S + aoff[m]);
            al[m] = *reinterpret_cast<const us8*>(S + (aoff[m] ^ 32));
        }
        #pragma unroll
        for (int n = 0; n < NF; ++n) {
            wh[n] = *reinterpret_cast<const us8*>(S + woff[n]);
            wl[n] = *reinterpret_cast<const us8*>(S + (woff[n] ^ 32));
        }
        #pragma unroll
        for (int m = 0; m < 4; ++m)
            #pragma unroll
            for (int n = 0; n < NF; ++n) {
                acc[m][n] = mfma_bf16(ah[m], wh[n], acc[m][n]);
                acc[m][n] = mfma_bf16(ah[m], wl[n], acc[m][n]);
                acc[m][n] = mfma_bf16(al[m], wh[n], acc[m][n]);
            }
        buf ^= 1;
    }

    // epilogue; C/D layout: col = lane&15, row = (lane>>4)*4 + reg
    float bvn[NF];
    #pragma unroll
    for (int n = 0; n < NF; ++n) bvn[n] = bias[bn + wn * (NF * 16) + n * 16 + lr];

    #pragma unroll
    for (int m = 0; m < 4; ++m) {
        #pragma unroll
        for (int j = 0; j < 4; ++j) {
            const int row = bm + wm * 64 + m * 16 + kc * 4 + j;
            #pragma unroll
            for (int n = 0; n < NF; ++n) {
                const int col = bn + wn * (NF * 16) + n * 16 + lr;
                float v = acc[m][n][j] + bvn[n];
                if constexpr (EPI == 1) v += Res[(size_t)row * N + col];
                if constexpr (EPI == 2) {
                    v = 0.5f * v * (1.0f + erff(v * 0.70710678118654752f));
                    unsigned short h = f2bf(v);
                    unsigned short l = f2bf(v - bf2f(h));
                    size_t o = (size_t)row * (size_t)(N * 2) + (size_t)(col >> 5) * 64 + (col & 31);
                    Cs[o]      = h;
                    Cs[o + 32] = l;
                } else {
                    Cf[(size_t)row * N + col] = v;
                }
            }
        }
    }
}

// ---------------------------------------------------------------- Local attention (fp32 in, split out)
__global__ __launch_bounds__(256)
void attn_kernel(const float* __restrict__ qkv, unsigned short* __restrict__ ctx)
{
    constexpr int RAD = 4;
    constexpr int TQ  = 64;
    constexpr int KROWS = TQ + 2 * RAD;   // 72
    constexpr int LDK = DHH + 4;          // 68

    __shared__ float Ks[KROWS][LDK];
    __shared__ float Vs[KROWS][LDK];

    const int t  = threadIdx.x;
    const int qt = blockIdx.x;
    const int b  = blockIdx.y;
    const int h  = blockIdx.z;
    const int q0 = qt * TQ;
    const float* base = qkv + ((size_t)b * SS) * QKV_N + h * DHH;

    for (int idx = t; idx < KROWS * (DHH / 4); idx += 256) {
        const int row = idx >> 4;
        const int c4  = idx & 15;
        const int gr  = q0 - RAD + row;
        float4 kv = make_float4(0.f, 0.f, 0.f, 0.f);
        float4 vv = kv;
        if (gr >= 0 && gr < SS) {
            const float* p = base + (size_t)gr * QKV_N;
            kv = *reinterpret_cast<const float4*>(p + DD     + c4 * 4);
            vv = *reinterpret_cast<const float4*>(p + 2 * DD + c4 * 4);
        }
        *reinterpret_cast<float4*>(&Ks[row][c4 * 4]) = kv;
        *reinterpret_cast<float4*>(&Vs[row][c4 * 4]) = vv;
    }
    __syncthreads();

    const int qi   = t >> 2;
    const int quad = t & 3;
    const int gq   = q0 + qi;
    const int d0   = quad * 16;

    const float* qp = base + (size_t)gq * QKV_N + d0;
    float4 q[4];
    #pragma unroll
    for (int i = 0; i < 4; ++i) q[i] = *reinterpret_cast<const float4*>(qp + i * 4);

    float s[9];
    #pragma unroll
    for (int j = 0; j < 9; ++j) {
        const float* kr = &Ks[qi + j][d0];
        float p = 0.f;
        #pragma unroll
        for (int i = 0; i < 4; ++i) {
            const float4 k4 = *reinterpret_cast<const float4*>(kr + i * 4);
            p += q[i].x * k4.x + q[i].y * k4.y + q[i].z * k4.z + q[i].w * k4.w;
        }
        p += __shfl_xor(p, 1);
        p += __shfl_xor(p, 2);
        const int gk = gq + j - RAD;
        s[j] = (gk >= 0 && gk < SS) ? p * 0.125f : -INFINITY;
    }
    float mx = s[0];
    #pragma unroll
    for (int j = 1; j < 9; ++j) mx = fmaxf(mx, s[j]);
    float pr[9]; float l = 0.f;
    #pragma unroll
    for (int j = 0; j < 9; ++j) { pr[j] = __expf(s[j] - mx); l += pr[j]; }
    const float inv = 1.0f / l;

    float o[16];
    #pragma unroll
    for (int i = 0; i < 16; ++i) o[i] = 0.f;
    #pragma unroll
    for (int j = 0; j < 9; ++j) {
        const float pj = pr[j] * inv;
        const float* vr = &Vs[qi + j][d0];
        #pragma unroll
        for (int i = 0; i < 16; i += 4) {
            const float4 v4 = *reinterpret_cast<const float4*>(vr + i);
            o[i]     = fmaf(pj, v4.x, o[i]);
            o[i + 1] = fmaf(pj, v4.y, o[i + 1]);
            o[i + 2] = fmaf(pj, v4.z, o[i + 2]);
            o[i + 3] = fmaf(pj, v4.w, o[i + 3]);
        }
    }
    const int col0 = h * DHH + d0;
    unsigned short* op = ctx + (size_t)(b * SS + gq) * 1024
                       + (size_t)(col0 >> 5) * 64 + (col0 & 31);
    us8 h0, h1, l0, l1;
    #pragma unroll
    for (int i = 0; i < 8; ++i) {
        h0[i] = f2bf(o[i]);      l0[i] = f2bf(o[i]     - bf2f(h0[i]));
        h1[i] = f2bf(o[8 + i]);  l1[i] = f2bf(o[8 + i] - bf2f(h1[i]));
    }
    *reinterpret_cast<us8*>(op)      = h0;
    *reinterpret_cast<us8*>(op + 8)  = h1;
    *reinterpret_cast<us8*>(op + 32) = l0;
    *reinterpret_cast<us8*>(op + 40) = l1;
}

// ---------------------------------------------------------------- launch
extern "C" void kernel_launch(void* const* d_in, const int* in_sizes, int n_in,
                              void* d_out, int out_size, void* d_ws, size_t ws_size,
                              hipStream_t stream)
{
    const float* x     = (const float*)d_in[0];
    const float* w_in  = (const float*)d_in[1];
    const float* b_in  = (const float*)d_in[2];
    const float* w_out = (const float*)d_in[3];
    const float* b_out = (const float*)d_in[4];
    const float* w_ff1 = (const float*)d_in[5];
    const float* b_ff1 = (const float*)d_in[6];
    const float* w_ff2 = (const float*)d_in[7];
    const float* b_ff2 = (const float*)d_in[8];
    const float* ln1_g = (const float*)d_in[9];
    const float* ln1_b = (const float*)d_in[10];
    const float* ln2_g = (const float*)d_in[11];
    const float* ln2_b = (const float*)d_in[12];
    float* out = (float*)d_out;

    // workspace layout (bytes):
    // [0,16M)    lnq   split [8192][512]    (LN out, reused for LN2)
    // [16M,32M)  x1    fp32  [8192][512]
    // [32M,48M)  ctxs  split [8192][512]    \ overlaid later by
    // [48M,96M)  qkv   fp32  [8192][1536]   / ffh split [8192][2048] (67MB)
    // [99.1M..]  weights split (wqs|wos|w1s contiguous, then w2s)
    char* ws = (char*)d_ws;
    unsigned short* lnq  = (unsigned short*)ws;
    float*          x1   = (float*)(ws + 16777216);
    unsigned short* ctxs = (unsigned short*)(ws + 2 * 16777216);
    float*          qkv  = (float*)(ws + 3 * 16777216);
    unsigned short* ffh  = (unsigned short*)(ws + 2 * 16777216);   // 67,108,864 B
    unsigned short* wqs  = (unsigned short*)(ws + 2 * 16777216 + 67108864);
    unsigned short* wos  = wqs + (size_t)1536 * 1024;
    unsigned short* w1s  = wos + (size_t)512 * 1024;
    unsigned short* w2s  = w1s + (size_t)2048 * 1024;

    // weight conversions: w_in|w_out|w_ff1 fused (4096 rows, K=512), w_ff2 separate
    conv3<<<1024, 256, 0, stream>>>(w_in, w_out, w_ff1, wqs);
    conv_split<<<512, 256, 0, stream>>>(w_ff2, w2s, 512 * 2048 / 8, 2048);

    // 1. LN1 -> split
    ln_kernel<<<MM, 128, 0, stream>>>(x, ln1_g, ln1_b, lnq);

    // 2. QKV: [8192,512]x[1536,512]^T -> fp32 qkv   (grid 768 = 3 waves of blocks/CU)
    gemm_tile<128, 0><<<dim3(QKV_N / 128, MM / 128), 256, 0, stream>>>(
        lnq, wqs, b_in, nullptr, qkv, nullptr, QKV_N, 512);

    // 3. local attention -> split ctx
    attn_kernel<<<dim3(SS / 64, BB, HH), 256, 0, stream>>>(qkv, ctxs);

    // 4. out-proj + residual: x1 = x + ctx @ out_w^T + b   (BN=64: grid 512, 3 blocks/CU)
    gemm_tile<64, 1><<<dim3(DD / 64, MM / 128), 256, 0, stream>>>(
        ctxs, wos, b_out, x, x1, nullptr, DD, 512);

    // 5. LN2 -> split
    ln_kernel<<<MM, 128, 0, stream>>>(x1, ln2_g, ln2_b, lnq);

    // 6. FF1 + GELU -> split ffh   (grid 1024)
    gemm_tile<128, 2><<<dim3(DFF / 128, MM / 128), 256, 0, stream>>>(
        lnq, w1s, b_ff1, nullptr, nullptr, ffh, DFF, 512);

    // 7. FF2 + residual: out = x1 + ffh @ ff_w2^T + b   (BN=64: grid 512, K=2048)
    gemm_tile<64, 1><<<dim3(DD / 64, MM / 128), 256, 0, stream>>>(
        ffh, w2s, b_ff2, x1, out, nullptr, DD, 2048);
}

// Round 9
// 202.329 us; speedup vs baseline: 3.5032x; 1.0370x over previous
//
#include <hip/hip_runtime.h>
#include <hip/hip_bf16.h>
#include <math.h>

// Problem constants
#define BB 4
#define SS 2048
#define DD 512
#define HH 8
#define DHH 64
#define DFF 2048
#define MM (BB*SS)          // 8192 rows
#define QKV_N (3*DD)        // 1536

typedef float  f32x4  __attribute__((ext_vector_type(4)));
typedef __bf16 bf16x8 __attribute__((ext_vector_type(8)));
typedef unsigned short us8 __attribute__((ext_vector_type(8)));
typedef unsigned short us4 __attribute__((ext_vector_type(4)));

// ---- bf16 helpers (RNE, finite inputs) ----
__device__ __forceinline__ unsigned short f2bf(float v) {
    unsigned int u = __float_as_uint(v);
    unsigned int r = (u + 0x7fffu + ((u >> 16) & 1u)) >> 16;
    return (unsigned short)r;
}
__device__ __forceinline__ float bf2f(unsigned short h) {
    return __uint_as_float(((unsigned int)h) << 16);
}

__device__ __forceinline__ f32x4 mfma_bf16(us8 a, us8 b, f32x4 c) {
    return __builtin_amdgcn_mfma_f32_16x16x32_bf16(
        __builtin_bit_cast(bf16x8, a), __builtin_bit_cast(bf16x8, b), c, 0, 0, 0);
}

__device__ __forceinline__ void gload_lds16(const void* gsrc, void* ldst) {
    __builtin_amdgcn_global_load_lds(
        (const __attribute__((address_space(1))) void*)gsrc,
        (__attribute__((address_space(3))) void*)ldst, 16, 0, 0);
}

// Split-bf16 global layout: per row of K elements -> K/32 blocks of 128B:
// [32 x bf16 hi][32 x bf16 lo]. ushort index: row*2K + (k/32)*64 + (k%32); lo at +32.

// ---------------------------------------------------------------- LayerNorm -> split bf16
__global__ __launch_bounds__(128)
void ln_kernel(const float* __restrict__ x, const float* __restrict__ g,
               const float* __restrict__ beta, unsigned short* __restrict__ outp)
{
    const int row = blockIdx.x;
    const int t = threadIdx.x;               // 128 threads, 4 floats each
    const float4 v = reinterpret_cast<const float4*>(x + (size_t)row * DD)[t];

    float s  = v.x + v.y + v.z + v.w;
    float s2 = v.x*v.x + v.y*v.y + v.z*v.z + v.w*v.w;
    #pragma unroll
    for (int off = 32; off >= 1; off >>= 1) {
        s  += __shfl_xor(s,  off);
        s2 += __shfl_xor(s2, off);
    }
    __shared__ float red[2][2];
    const int lane = t & 63, wid = t >> 6;
    if (lane == 0) { red[wid][0] = s; red[wid][1] = s2; }
    __syncthreads();
    const float ts  = red[0][0] + red[1][0];
    const float ts2 = red[0][1] + red[1][1];
    const float mu  = ts * (1.0f / DD);
    const float var = ts2 * (1.0f / DD) - mu * mu;
    const float rs  = rsqrtf(var + 1e-5f);

    const float4 gv = reinterpret_cast<const float4*>(g)[t];
    const float4 bv = reinterpret_cast<const float4*>(beta)[t];
    float vals[4];
    vals[0] = (v.x - mu) * rs * gv.x + bv.x;
    vals[1] = (v.y - mu) * rs * gv.y + bv.y;
    vals[2] = (v.z - mu) * rs * gv.z + bv.z;
    vals[3] = (v.w - mu) * rs * gv.w + bv.w;

    us4 hv, lv;
    #pragma unroll
    for (int i = 0; i < 4; ++i) {
        hv[i] = f2bf(vals[i]);
        lv[i] = f2bf(vals[i] - bf2f(hv[i]));
    }
    const int k = t * 4;
    size_t o = (size_t)row * 1024 + (size_t)(k >> 5) * 64 + (k & 31);
    *reinterpret_cast<us4*>(outp + o)      = hv;
    *reinterpret_cast<us4*>(outp + o + 32) = lv;
}

// ---------------------------------------------------------------- fp32 -> split bf16 (weights)
__global__ __launch_bounds__(256)
void conv_split(const float* __restrict__ in, unsigned short* __restrict__ outp,
                int total /* R*K/8 */, int K)
{
    const int gid = blockIdx.x * 256 + threadIdx.x;
    if (gid >= total) return;
    const int cpr = K >> 3;
    const int r = gid / cpr;
    const int k0 = (gid - r * cpr) * 8;
    const float* p = in + (size_t)r * K + k0;
    us8 h, l;
    #pragma unroll
    for (int i = 0; i < 8; ++i) {
        float v = p[i];
        h[i] = f2bf(v);
        l[i] = f2bf(v - bf2f(h[i]));
    }
    size_t o = (size_t)r * (size_t)(K * 2) + (size_t)(k0 >> 5) * 64 + (k0 & 31);
    *reinterpret_cast<us8*>(outp + o)      = h;
    *reinterpret_cast<us8*>(outp + o + 32) = l;
}

// Fused conversion of w_in (1536x512) + w_out (512x512) + w_ff1 (2048x512)
// into one contiguous split region (rows 0..4095, K=512).
__global__ __launch_bounds__(256)
void conv3(const float* __restrict__ w_in, const float* __restrict__ w_out,
           const float* __restrict__ w_ff1, unsigned short* __restrict__ dst)
{
    const int gid = blockIdx.x * 256 + threadIdx.x;   // 4096 rows * 64 us8
    const int r  = gid >> 6;
    const int k0 = (gid & 63) * 8;
    const float* src = (r < 1536) ? w_in  + (size_t)r * 512 + k0
                     : (r < 2048) ? w_out + (size_t)(r - 1536) * 512 + k0
                                  : w_ff1 + (size_t)(r - 2048) * 512 + k0;
    us8 h, l;
    #pragma unroll
    for (int i = 0; i < 8; ++i) {
        float v = src[i];
        h[i] = f2bf(v);
        l[i] = f2bf(v - bf2f(h[i]));
    }
    size_t o = (size_t)r * 1024 + (size_t)(k0 >> 5) * 64 + (k0 & 31);
    *reinterpret_cast<us8*>(dst + o)      = h;
    *reinterpret_cast<us8*>(dst + o + 32) = l;
}

// ---------------------------------------------------------------- split-bf16 MFMA GEMM
// BM=128 fixed, BN in {128, 64}. 4 waves (2x2). 2-barrier double-buffered loop
// (proven m97-style structure). BN=64: 48KB LDS -> 3 blocks/CU (12 waves) — the
// measured-better regime (round-8 A/B: FF2@BN=64 < FF1@BN=128 despite 4x K).
// XCD-aware bijective block swizzle (requires nwg % 8 == 0).
// EPI: 0 = bias -> fp32 Cf; 1 = bias + Res -> fp32 Cf; 2 = bias + GELU -> split Cs
template<int BN, int EPI>
__global__ __launch_bounds__(256, 3)
void gemm_tile(const unsigned short* __restrict__ Ax, const unsigned short* __restrict__ Wx,
               const float* __restrict__ bias, const float* __restrict__ Res,
               float* __restrict__ Cf, unsigned short* __restrict__ Cs,
               int N, int K)
{
    constexpr int NF   = BN / 32;          // n-frags per wave (4 or 2)
    constexpr int AUSH = 128 * 64;         // ushorts per A buffer
    constexpr int BUSH = BN * 64;
    __shared__ unsigned short smem[2][AUSH + BUSH];

    const int tid  = threadIdx.x;
    const int wave = tid >> 6, lane = tid & 63;
    const int wm = wave >> 1, wn = wave & 1;
    const int lr = lane & 15, kc = lane >> 4;

    // XCD swizzle: contiguous chunks of the flat grid per XCD
    const int nwg = gridDim.x * gridDim.y;
    int bid = blockIdx.y * gridDim.x + blockIdx.x;
    bid = (bid & 7) * (nwg >> 3) + (bid >> 3);
    const int bn = (bid % gridDim.x) * BN;
    const int bm = (bid / gridDim.x) * 128;

    const int K2  = K * 2;
    const int nkb = K >> 5;

    // LDS ushort offsets of hi fragments (lo = ^32); chunk swizzled by row&7
    int aoff[4], woff[NF];
    #pragma unroll
    for (int m = 0; m < 4; ++m) {
        const int ra = wm * 64 + m * 16 + lr;
        aoff[m] = ra * 64 + ((kc ^ (ra & 7)) * 8);
    }
    #pragma unroll
    for (int n = 0; n < NF; ++n) {
        const int rw = wn * (NF * 16) + n * 16 + lr;
        woff[n] = AUSH + rw * 64 + ((kc ^ (rw & 7)) * 8);
    }

    f32x4 acc[4][NF];
    #pragma unroll
    for (int i = 0; i < 4; ++i)
        #pragma unroll
        for (int j = 0; j < NF; ++j) acc[i][j] = (f32x4){0.f, 0.f, 0.f, 0.f};

    // staging: thread covers LDS linear off; row = off>>6, slot = (off>>3)&7,
    // source logical chunk = slot ^ (row&7)  (inverse of read swizzle)
    auto stage = [&](int buf, int kb) {
        #pragma unroll
        for (int j = 0; j < 4; ++j) {
            const int off = j * 2048 + tid * 8;
            const int row = off >> 6;
            const int q   = ((off >> 3) & 7) ^ (row & 7);
            gload_lds16(Ax + (size_t)(bm + row) * K2 + (size_t)kb * 64 + q * 8,
                        &smem[buf][off]);
        }
        #pragma unroll
        for (int j = 0; j < BN / 32; ++j) {
            const int off = j * 2048 + tid * 8;
            const int row = off >> 6;
            const int q   = ((off >> 3) & 7) ^ (row & 7);
            gload_lds16(Wx + (size_t)(bn + row) * K2 + (size_t)kb * 64 + q * 8,
                        &smem[buf][AUSH + off]);
        }
    };

    stage(0, 0);
    int buf = 0;
    for (int kb = 0; kb < nkb; ++kb) {
        __syncthreads();                       // stage(buf) drained; prev reads done
        if (kb + 1 < nkb) stage(buf ^ 1, kb + 1);

        const unsigned short* S = smem[buf];
        us8 ah[4], al[4], wh[NF], wl[NF];
        #pragma unroll
        for (int m = 0; m < 4; ++m) {
            ah[m] = *reinterpret_cast<const us8*>(S + aoff[m]);
            al[m] = *reinterpret_cast<const us8*>(S + (aoff[m] ^ 32));
        }
        #pragma unroll
        for (int n = 0; n < NF; ++n) {
            wh[n] = *reinterpret_cast<const us8*>(S + woff[n]);
            wl[n] = *reinterpret_cast<const us8*>(S + (woff[n] ^ 32));
        }
        #pragma unroll
        for (int m = 0; m < 4; ++m)
            #pragma unroll
            for (int n = 0; n < NF; ++n) {
                acc[m][n] = mfma_bf16(ah[m], wh[n], acc[m][n]);
                acc[m][n] = mfma_bf16(ah[m], wl[n], acc[m][n]);
                acc[m][n] = mfma_bf16(al[m], wh[n], acc[m][n]);
            }
        buf ^= 1;
    }

    // epilogue; C/D layout: col = lane&15, row = (lane>>4)*4 + reg
    float bvn[NF];
    #pragma unroll
    for (int n = 0; n < NF; ++n) bvn[n] = bias[bn + wn * (NF * 16) + n * 16 + lr];

    #pragma unroll
    for (int m = 0; m < 4; ++m) {
        #pragma unroll
        for (int j = 0; j < 4; ++j) {
            const int row = bm + wm * 64 + m * 16 + kc * 4 + j;
            #pragma unroll
            for (int n = 0; n < NF; ++n) {
                const int col = bn + wn * (NF * 16) + n * 16 + lr;
                float v = acc[m][n][j] + bvn[n];
                if constexpr (EPI == 1) v += Res[(size_t)row * N + col];
                if constexpr (EPI == 2) {
                    v = 0.5f * v * (1.0f + erff(v * 0.70710678118654752f));
                    unsigned short h = f2bf(v);
                    unsigned short l = f2bf(v - bf2f(h));
                    size_t o = (size_t)row * (size_t)(N * 2) + (size_t)(col >> 5) * 64 + (col & 31);
                    Cs[o]      = h;
                    Cs[o + 32] = l;
                } else {
                    Cf[(size_t)row * N + col] = v;
                }
            }
        }
    }
}

// ---------------------------------------------------------------- Local attention (fp32 in, split out)
__global__ __launch_bounds__(256)
void attn_kernel(const float* __restrict__ qkv, unsigned short* __restrict__ ctx)
{
    constexpr int RAD = 4;
    constexpr int TQ  = 64;
    constexpr int KROWS = TQ + 2 * RAD;   // 72
    constexpr int LDK = DHH + 4;          // 68

    __shared__ float Ks[KROWS][LDK];
    __shared__ float Vs[KROWS][LDK];

    const int t  = threadIdx.x;
    const int qt = blockIdx.x;
    const int b  = blockIdx.y;
    const int h  = blockIdx.z;
    const int q0 = qt * TQ;
    const float* base = qkv + ((size_t)b * SS) * QKV_N + h * DHH;

    for (int idx = t; idx < KROWS * (DHH / 4); idx += 256) {
        const int row = idx >> 4;
        const int c4  = idx & 15;
        const int gr  = q0 - RAD + row;
        float4 kv = make_float4(0.f, 0.f, 0.f, 0.f);
        float4 vv = kv;
        if (gr >= 0 && gr < SS) {
            const float* p = base + (size_t)gr * QKV_N;
            kv = *reinterpret_cast<const float4*>(p + DD     + c4 * 4);
            vv = *reinterpret_cast<const float4*>(p + 2 * DD + c4 * 4);
        }
        *reinterpret_cast<float4*>(&Ks[row][c4 * 4]) = kv;
        *reinterpret_cast<float4*>(&Vs[row][c4 * 4]) = vv;
    }
    __syncthreads();

    const int qi   = t >> 2;
    const int quad = t & 3;
    const int gq   = q0 + qi;
    const int d0   = quad * 16;

    const float* qp = base + (size_t)gq * QKV_N + d0;
    float4 q[4];
    #pragma unroll
    for (int i = 0; i < 4; ++i) q[i] = *reinterpret_cast<const float4*>(qp + i * 4);

    float s[9];
    #pragma unroll
    for (int j = 0; j < 9; ++j) {
        const float* kr = &Ks[qi + j][d0];
        float p = 0.f;
        #pragma unroll
        for (int i = 0; i < 4; ++i) {
            const float4 k4 = *reinterpret_cast<const float4*>(kr + i * 4);
            p += q[i].x * k4.x + q[i].y * k4.y + q[i].z * k4.z + q[i].w * k4.w;
        }
        p += __shfl_xor(p, 1);
        p += __shfl_xor(p, 2);
        const int gk = gq + j - RAD;
        s[j] = (gk >= 0 && gk < SS) ? p * 0.125f : -INFINITY;
    }
    float mx = s[0];
    #pragma unroll
    for (int j = 1; j < 9; ++j) mx = fmaxf(mx, s[j]);
    float pr[9]; float l = 0.f;
    #pragma unroll
    for (int j = 0; j < 9; ++j) { pr[j] = __expf(s[j] - mx); l += pr[j]; }
    const float inv = 1.0f / l;

    float o[16];
    #pragma unroll
    for (int i = 0; i < 16; ++i) o[i] = 0.f;
    #pragma unroll
    for (int j = 0; j < 9; ++j) {
        const float pj = pr[j] * inv;
        const float* vr = &Vs[qi + j][d0];
        #pragma unroll
        for (int i = 0; i < 16; i += 4) {
            const float4 v4 = *reinterpret_cast<const float4*>(vr + i);
            o[i]     = fmaf(pj, v4.x, o[i]);
            o[i + 1] = fmaf(pj, v4.y, o[i + 1]);
            o[i + 2] = fmaf(pj, v4.z, o[i + 2]);
            o[i + 3] = fmaf(pj, v4.w, o[i + 3]);
        }
    }
    const int col0 = h * DHH + d0;
    unsigned short* op = ctx + (size_t)(b * SS + gq) * 1024
                       + (size_t)(col0 >> 5) * 64 + (col0 & 31);
    us8 h0, h1, l0, l1;
    #pragma unroll
    for (int i = 0; i < 8; ++i) {
        h0[i] = f2bf(o[i]);      l0[i] = f2bf(o[i]     - bf2f(h0[i]));
        h1[i] = f2bf(o[8 + i]);  l1[i] = f2bf(o[8 + i] - bf2f(h1[i]));
    }
    *reinterpret_cast<us8*>(op)      = h0;
    *reinterpret_cast<us8*>(op + 8)  = h1;
    *reinterpret_cast<us8*>(op + 32) = l0;
    *reinterpret_cast<us8*>(op + 40) = l1;
}

// ---------------------------------------------------------------- launch
extern "C" void kernel_launch(void* const* d_in, const int* in_sizes, int n_in,
                              void* d_out, int out_size, void* d_ws, size_t ws_size,
                              hipStream_t stream)
{
    const float* x     = (const float*)d_in[0];
    const float* w_in  = (const float*)d_in[1];
    const float* b_in  = (const float*)d_in[2];
    const float* w_out = (const float*)d_in[3];
    const float* b_out = (const float*)d_in[4];
    const float* w_ff1 = (const float*)d_in[5];
    const float* b_ff1 = (const float*)d_in[6];
    const float* w_ff2 = (const float*)d_in[7];
    const float* b_ff2 = (const float*)d_in[8];
    const float* ln1_g = (const float*)d_in[9];
    const float* ln1_b = (const float*)d_in[10];
    const float* ln2_g = (const float*)d_in[11];
    const float* ln2_b = (const float*)d_in[12];
    float* out = (float*)d_out;

    // workspace layout (bytes):
    // [0,16M)    lnq   split [8192][512]    (LN out, reused for LN2)
    // [16M,32M)  x1    fp32  [8192][512]
    // [32M,48M)  ctxs  split [8192][512]    \ overlaid later by
    // [48M,96M)  qkv   fp32  [8192][1536]   / ffh split [8192][2048] (67MB)
    // [99.1M..]  weights split (wqs|wos|w1s contiguous, then w2s)
    char* ws = (char*)d_ws;
    unsigned short* lnq  = (unsigned short*)ws;
    float*          x1   = (float*)(ws + 16777216);
    unsigned short* ctxs = (unsigned short*)(ws + 2 * 16777216);
    float*          qkv  = (float*)(ws + 3 * 16777216);
    unsigned short* ffh  = (unsigned short*)(ws + 2 * 16777216);   // 67,108,864 B
    unsigned short* wqs  = (unsigned short*)(ws + 2 * 16777216 + 67108864);
    unsigned short* wos  = wqs + (size_t)1536 * 1024;
    unsigned short* w1s  = wos + (size_t)512 * 1024;
    unsigned short* w2s  = w1s + (size_t)2048 * 1024;

    // weight conversions: w_in|w_out|w_ff1 fused (4096 rows, K=512), w_ff2 separate
    conv3<<<1024, 256, 0, stream>>>(w_in, w_out, w_ff1, wqs);
    conv_split<<<512, 256, 0, stream>>>(w_ff2, w2s, 512 * 2048 / 8, 2048);

    // 1. LN1 -> split
    ln_kernel<<<MM, 128, 0, stream>>>(x, ln1_g, ln1_b, lnq);

    // 2. QKV: [8192,512]x[1536,512]^T -> fp32 qkv   (BN=64: grid 1536, 3 blocks/CU)
    gemm_tile<64, 0><<<dim3(QKV_N / 64, MM / 128), 256, 0, stream>>>(
        lnq, wqs, b_in, nullptr, qkv, nullptr, QKV_N, 512);

    // 3. local attention -> split ctx
    attn_kernel<<<dim3(SS / 64, BB, HH), 256, 0, stream>>>(qkv, ctxs);

    // 4. out-proj + residual: x1 = x + ctx @ out_w^T + b   (BN=64: grid 512, 3 blocks/CU)
    gemm_tile<64, 1><<<dim3(DD / 64, MM / 128), 256, 0, stream>>>(
        ctxs, wos, b_out, x, x1, nullptr, DD, 512);

    // 5. LN2 -> split
    ln_kernel<<<MM, 128, 0, stream>>>(x1, ln2_g, ln2_b, lnq);

    // 6. FF1 + GELU -> split ffh   (BN=64: grid 2048, 3 blocks/CU)
    gemm_tile<64, 2><<<dim3(DFF / 64, MM / 128), 256, 0, stream>>>(
        lnq, w1s, b_ff1, nullptr, nullptr, ffh, DFF, 512);

    // 7. FF2 + residual: out = x1 + ffh @ ff_w2^T + b   (BN=64: grid 512, K=2048)
    gemm_tile<64, 1><<<dim3(DD / 64, MM / 128), 256, 0, stream>>>(
        ffh, w2s, b_ff2, x1, out, nullptr, DD, 2048);
}